// Round 7
// baseline (308.694 us; speedup 1.0000x reference)
//
#include <hip/hip_runtime.h>

// GraphSAGE 2-layer, fp32 in/out. N=100000, E=1.6M, D: 64 -> 64 -> 32.
// Transform-first on BOTH layers. Gathered tensors compressed to 64 B rows:
//   t1l: fp8 e4m3 (64 dims), t2l: bf16 (32 dims).
// R6 lesson: agg gather is bound by L2-miss line traffic (~1.5 TB/s, ~51 MB
// compulsory: 8 XCDs x 6.4 MB table); R5's wave-per-node layout is near
// floor. R6's shfl-broadcast variant regressed (VGPR 16->48, occ 66->41%).
// This round: revert aggs to R5 (+4-chain MLP in agg1), fuse bhist+bscan
// into the gemm1 launch (block-split + last-block scan) to cut launches.

typedef __attribute__((ext_vector_type(4))) float f4;
typedef __attribute__((ext_vector_type(2))) float f2;
typedef __attribute__((ext_vector_type(8))) unsigned short us8;
typedef __attribute__((ext_vector_type(4))) unsigned short us4;

#define BSHIFT 9
#define BSZ (1 << BSHIFT)   // 512 nodes per bucket
#define NBMAX 256

static __device__ inline unsigned short f2bf(float f) {
    union { float f; unsigned u; } v; v.f = f;
    unsigned u = v.u;
    u = (u + 0x7FFFu + ((u >> 16) & 1u)) >> 16;   // RNE
    return (unsigned short)u;
}
static __device__ inline float bf2f(unsigned short h) {
    union { unsigned u; float f; } v; v.u = ((unsigned)h) << 16; return v.f;
}

// ---------------- Fused: GEMM1 (blocks [0,gb)) | bhist+bscan (blocks [gb,gb+NBH)) ----
// GEMM1: t1l(fp8) = x@Wl, t1r(f32) = x@Wr.
// bhist: LDS-aggregated bucket histogram; LAST bhist block performs the
// serial bucket scan (deterministic, no spin).
__global__ __launch_bounds__(256) void k_g1h(const float* __restrict__ x,
                                             const float* __restrict__ Wl,
                                             const float* __restrict__ Wr, int N, int gb,
                                             unsigned char* __restrict__ t1l8,
                                             float* __restrict__ t1r,
                                             const int* __restrict__ dst, int E, int chunk,
                                             int NBH, int NB,
                                             int* __restrict__ bucket_cnt,
                                             int* __restrict__ done,
                                             int* __restrict__ bucket_base,
                                             int* __restrict__ bucket_cur,
                                             int* __restrict__ row_off) {
    __shared__ float smem[64 * 68 + 2 * 64 * 64];
    int t = threadIdx.x;
    if ((int)blockIdx.x >= gb) {
        // ---- bhist part ----
        int* hist = (int*)smem;
        hist[t] = 0;
        __syncthreads();
        int bb = blockIdx.x - gb;
        int lo = bb * chunk, hi = min(lo + chunk, E);
        for (int e = lo + t; e < hi; e += 256) atomicAdd(&hist[dst[e] >> BSHIFT], 1);
        __syncthreads();
        if (t < NB) { int c = hist[t]; if (c) atomicAdd(&bucket_cnt[t], c); }
        __syncthreads();
        __threadfence();
        __shared__ int lastflag;
        if (t == 0) lastflag = (atomicAdd(done, 1) == NBH - 1) ? 1 : 0;
        __syncthreads();
        if (lastflag && t == 0) {
            __threadfence();
            int run = 0;
            for (int b = 0; b < NB; b++) {
                int v = atomicAdd(&bucket_cnt[b], 0);
                bucket_base[b] = run; bucket_cur[b] = run; run += v;
            }
            bucket_base[NB] = run;
            row_off[N] = E;
        }
        return;
    }
    // ---- GEMM1 part ----
    float* sA  = smem;                 // [64][68]
    float* sWl = smem + 64 * 68;       // [64][64]
    float* sWr = sWl + 64 * 64;
    int r0 = blockIdx.x * 64;
    for (int i = t; i < 1024; i += 256) {
        *(f4*)&sWl[i * 4] = *(const f4*)&Wl[i * 4];
        *(f4*)&sWr[i * 4] = *(const f4*)&Wr[i * 4];
    }
    {
        int row = t >> 4;
        int d0 = (t & 15) * 4;
#pragma unroll
        for (int kk = 0; kk < 4; kk++) {
            int r = row + kk * 16;
            f4 v = {0.f, 0.f, 0.f, 0.f};
            if (r0 + r < N) v = *(const f4*)&x[(size_t)(r0 + r) * 64 + d0];
            sA[(d0 + 0) * 68 + r] = v[0];
            sA[(d0 + 1) * 68 + r] = v[1];
            sA[(d0 + 2) * 68 + r] = v[2];
            sA[(d0 + 3) * 68 + r] = v[3];
        }
    }
    __syncthreads();
    int ty = t >> 4;
    int tx = t & 15;
    f4 accl[4] = {{0.f,0.f,0.f,0.f},{0.f,0.f,0.f,0.f},{0.f,0.f,0.f,0.f},{0.f,0.f,0.f,0.f}};
    f4 accr[4] = {{0.f,0.f,0.f,0.f},{0.f,0.f,0.f,0.f},{0.f,0.f,0.f,0.f},{0.f,0.f,0.f,0.f}};
#pragma unroll 4
    for (int d = 0; d < 64; d++) {
        f4 a  = *(const f4*)&sA[d * 68 + ty * 4];
        f4 wl = *(const f4*)&sWl[d * 64 + tx * 4];
        f4 wr = *(const f4*)&sWr[d * 64 + tx * 4];
#pragma unroll
        for (int r = 0; r < 4; r++) {
            accl[r] += a[r] * wl;
            accr[r] += a[r] * wr;
        }
    }
#pragma unroll
    for (int r = 0; r < 4; r++) {
        int rr = r0 + ty * 4 + r;
        if (rr < N) {
            unsigned w8 = __builtin_amdgcn_cvt_pk_fp8_f32(accl[r][0], accl[r][1], 0u, false);
            w8 = __builtin_amdgcn_cvt_pk_fp8_f32(accl[r][2], accl[r][3], w8, true);
            *(unsigned*)&t1l8[(size_t)rr * 64 + tx * 4] = w8;
            *(f4*)&t1r[(size_t)rr * 64 + tx * 4] = accr[r];
        }
    }
}

// ---------------- bscatter: group edges by dst bucket ----------------
__global__ __launch_bounds__(256) void k_bscatter(const int* __restrict__ src, const int* __restrict__ dst,
                                                  int E, int chunk, int NB,
                                                  int* __restrict__ bucket_cur,
                                                  unsigned int* __restrict__ bdata) {
    __shared__ int lcnt[NBMAX], lbase[NBMAX], lcur[NBMAX];
    int t = threadIdx.x;
    lcnt[t] = 0;
    __syncthreads();
    int lo = blockIdx.x * chunk, hi = min(lo + chunk, E);
    for (int e = lo + t; e < hi; e += 256) atomicAdd(&lcnt[dst[e] >> BSHIFT], 1);
    __syncthreads();
    if (t < NB) { int c = lcnt[t]; lcur[t] = 0; if (c) lbase[t] = atomicAdd(&bucket_cur[t], c); }
    __syncthreads();
    for (int e = lo + t; e < hi; e += 256) {
        int d = dst[e];
        int b = d >> BSHIFT;
        int pos = lbase[b] + atomicAdd(&lcur[b], 1);
        bdata[pos] = ((unsigned)(d & (BSZ - 1)) << 17) | (unsigned)src[e];  // src < 2^17
    }
}

// ---------------- bucket_csr: per-bucket fine histogram + scan ----------------
__global__ __launch_bounds__(256) void k_bucket_csr(const unsigned int* __restrict__ bdata,
                                                    const int* __restrict__ bucket_base,
                                                    int N, int* __restrict__ row_off,
                                                    int* __restrict__ col_src) {
    __shared__ int fh[BSZ];
    __shared__ int wtot[4];
    int t = threadIdx.x;
    int b = blockIdx.x;
    int ebase = bucket_base[b], eend = bucket_base[b + 1];
    fh[2 * t] = 0; fh[2 * t + 1] = 0;
    __syncthreads();
    for (int i = ebase + t; i < eend; i += 256) atomicAdd(&fh[bdata[i] >> 17], 1);
    __syncthreads();
    int a0 = fh[2 * t], a1 = fh[2 * t + 1];
    int psum = a0 + a1;
    int lane = t & 63, w = t >> 6;
    int v = psum;
    for (int off = 1; off < 64; off <<= 1) { int u = __shfl_up(v, off); if (lane >= off) v += u; }
    if (lane == 63) wtot[w] = v;
    __syncthreads();
    int wbase = 0;
    for (int i = 0; i < w; i++) wbase += wtot[i];
    int excl = wbase + v - psum;
    int e0 = excl, e1 = excl + a0;
    int n0 = (b << BSHIFT) + 2 * t, n1 = n0 + 1;
    if (n0 < N) row_off[n0] = ebase + e0;
    if (n1 < N) row_off[n1] = ebase + e1;
    fh[2 * t] = e0; fh[2 * t + 1] = e1;
    __syncthreads();
    for (int i = ebase + t; i < eend; i += 256) {
        unsigned vv = bdata[i];
        int dl = vv >> 17;
        int pos = atomicAdd(&fh[dl], 1);
        col_src[ebase + pos] = (int)(vv & 0x1FFFFu);
    }
}

// ---------------- GEMM 2: t2l(bf16) = h@W2l, t2r(f32) = h@W2r + b2 ----------------
__global__ __launch_bounds__(256) void k_gemm2(const float* __restrict__ h,
                                               const float* __restrict__ Wl,
                                               const float* __restrict__ Wr,
                                               const float* __restrict__ b2, int N,
                                               unsigned short* __restrict__ t2l,
                                               float* __restrict__ t2r) {
    __shared__ float sA[64 * 68];
    __shared__ float sWl[64 * 32];
    __shared__ float sWr[64 * 32];
    int t = threadIdx.x;
    int r0 = blockIdx.x * 64;
    for (int i = t; i < 512; i += 256) {
        *(f4*)&sWl[i * 4] = *(const f4*)&Wl[i * 4];
        *(f4*)&sWr[i * 4] = *(const f4*)&Wr[i * 4];
    }
    {
        int row = t >> 4;
        int d0 = (t & 15) * 4;
#pragma unroll
        for (int kk = 0; kk < 4; kk++) {
            int r = row + kk * 16;
            f4 v = {0.f, 0.f, 0.f, 0.f};
            if (r0 + r < N) v = *(const f4*)&h[(size_t)(r0 + r) * 64 + d0];
            sA[(d0 + 0) * 68 + r] = v[0];
            sA[(d0 + 1) * 68 + r] = v[1];
            sA[(d0 + 2) * 68 + r] = v[2];
            sA[(d0 + 3) * 68 + r] = v[3];
        }
    }
    __syncthreads();
    int ty = t >> 4;
    int tx = t & 15;
    int m  = tx >> 3;
    int c0 = (tx & 7) * 4;
    const float* sW = m ? sWr : sWl;
    f4 acc[4] = {{0.f,0.f,0.f,0.f},{0.f,0.f,0.f,0.f},{0.f,0.f,0.f,0.f},{0.f,0.f,0.f,0.f}};
#pragma unroll 4
    for (int d = 0; d < 64; d++) {
        f4 a = *(const f4*)&sA[d * 68 + ty * 4];
        f4 w = *(const f4*)&sW[d * 32 + c0];
#pragma unroll
        for (int r = 0; r < 4; r++) acc[r] += a[r] * w;
    }
    if (m) {
        f4 bias = *(const f4*)&b2[c0];
#pragma unroll
        for (int r = 0; r < 4; r++) {
            int rr = r0 + ty * 4 + r;
            if (rr < N) *(f4*)&t2r[(size_t)rr * 32 + c0] = acc[r] + bias;
        }
    } else {
#pragma unroll
        for (int r = 0; r < 4; r++) {
            int rr = r0 + ty * 4 + r;
            if (rr < N) {
                us4 lv;
#pragma unroll
                for (int j = 0; j < 4; j++) lv[j] = f2bf(acc[r][j]);
                *(us4*)&t2l[(size_t)rr * 32 + c0] = lv;
            }
        }
    }
}

// ---------------- Layer-1 gather: h = relu(mean(t1l[nbrs]) + t1r + b1) ----------------
// wave/node; lane = (slot 0..3, dimgroup 0..15); 4 independent chains (MLP).
__global__ void k_agg1(const unsigned char* __restrict__ t1l8, const int* __restrict__ row_off,
                       const int* __restrict__ col_src, const float* __restrict__ b1,
                       int N, float* __restrict__ h /* == t1r, in-place */) {
    int wid = (blockIdx.x * blockDim.x + threadIdx.x) >> 6;
    int lane = threadIdx.x & 63;
    if (wid >= N) return;
    int beg = row_off[wid], end = row_off[wid + 1];
    int slot = lane >> 4;     // 0..3
    int g4 = (lane & 15) * 4; // dims g4..g4+3
    f4 s0 = {0.f,0.f,0.f,0.f}, s1 = {0.f,0.f,0.f,0.f};
    f4 s2 = {0.f,0.f,0.f,0.f}, s3 = {0.f,0.f,0.f,0.f};
    int k = beg + slot;
    for (; k + 12 < end; k += 16) {
        unsigned ua = *(const unsigned*)&t1l8[(size_t)col_src[k] * 64 + g4];
        unsigned ub = *(const unsigned*)&t1l8[(size_t)col_src[k + 4] * 64 + g4];
        unsigned uc = *(const unsigned*)&t1l8[(size_t)col_src[k + 8] * 64 + g4];
        unsigned ud = *(const unsigned*)&t1l8[(size_t)col_src[k + 12] * 64 + g4];
        f2 a0 = __builtin_amdgcn_cvt_pk_f32_fp8(ua, false);
        f2 a1 = __builtin_amdgcn_cvt_pk_f32_fp8(ua, true);
        f2 b0 = __builtin_amdgcn_cvt_pk_f32_fp8(ub, false);
        f2 b1x = __builtin_amdgcn_cvt_pk_f32_fp8(ub, true);
        f2 c0 = __builtin_amdgcn_cvt_pk_f32_fp8(uc, false);
        f2 c1 = __builtin_amdgcn_cvt_pk_f32_fp8(uc, true);
        f2 d0 = __builtin_amdgcn_cvt_pk_f32_fp8(ud, false);
        f2 d1 = __builtin_amdgcn_cvt_pk_f32_fp8(ud, true);
        s0[0] += a0[0]; s0[1] += a0[1]; s0[2] += a1[0]; s0[3] += a1[1];
        s1[0] += b0[0]; s1[1] += b0[1]; s1[2] += b1x[0]; s1[3] += b1x[1];
        s2[0] += c0[0]; s2[1] += c0[1]; s2[2] += c1[0]; s2[3] += c1[1];
        s3[0] += d0[0]; s3[1] += d0[1]; s3[2] += d1[0]; s3[3] += d1[1];
    }
    for (; k < end; k += 4) {
        unsigned ua = *(const unsigned*)&t1l8[(size_t)col_src[k] * 64 + g4];
        f2 a0 = __builtin_amdgcn_cvt_pk_f32_fp8(ua, false);
        f2 a1 = __builtin_amdgcn_cvt_pk_f32_fp8(ua, true);
        s0[0] += a0[0]; s0[1] += a0[1]; s0[2] += a1[0]; s0[3] += a1[1];
    }
    f4 sa = (s0 + s1) + (s2 + s3);
#pragma unroll
    for (int j = 0; j < 4; j++) {
        float v = sa[j];
        v += __shfl_xor(v, 16);
        v += __shfl_xor(v, 32);
        sa[j] = v;
    }
    if (slot == 0) {
        float deg = (float)(end - beg);
        float inv = deg > 0.f ? 1.f / deg : 0.f;
        f4 rr = *(const f4*)&h[(size_t)wid * 64 + g4];
        f4 bb = *(const f4*)&b1[g4];
        f4 o;
#pragma unroll
        for (int j = 0; j < 4; j++) {
            float v = sa[j] * inv + rr[j] + bb[j];
            o[j] = v > 0.f ? v : 0.f;
        }
        *(f4*)&h[(size_t)wid * 64 + g4] = o;
    }
}

// ---------------- Layer-2 gather: out = mean(t2l[nbrs]) + t2r ----------------
__global__ void k_agg2(const unsigned short* __restrict__ t2l, const float* __restrict__ t2r,
                       const int* __restrict__ row_off, const int* __restrict__ col_src,
                       int N, float* __restrict__ out) {
    int wid = (blockIdx.x * blockDim.x + threadIdx.x) >> 6;
    int lane = threadIdx.x & 63;
    if (wid >= N) return;
    int beg = row_off[wid], end = row_off[wid + 1];
    int slot = lane >> 2;
    int d8 = (lane & 3) * 8;
    f4 sa = {0.f,0.f,0.f,0.f}, sb = {0.f,0.f,0.f,0.f};
    f4 ta = {0.f,0.f,0.f,0.f}, tb = {0.f,0.f,0.f,0.f};
    int k = beg + slot;
    for (; k + 16 < end; k += 32) {
        us8 va = *(const us8*)&t2l[(size_t)col_src[k] * 32 + d8];
        us8 vb = *(const us8*)&t2l[(size_t)col_src[k + 16] * 32 + d8];
#pragma unroll
        for (int j = 0; j < 4; j++) {
            sa[j] += bf2f(va[j]);     sb[j] += bf2f(va[j + 4]);
            ta[j] += bf2f(vb[j]);     tb[j] += bf2f(vb[j + 4]);
        }
    }
    if (k < end) {
        us8 va = *(const us8*)&t2l[(size_t)col_src[k] * 32 + d8];
#pragma unroll
        for (int j = 0; j < 4; j++) { sa[j] += bf2f(va[j]); sb[j] += bf2f(va[j + 4]); }
    }
    sa += ta; sb += tb;
#pragma unroll
    for (int j = 0; j < 4; j++) {
        float v = sa[j];
        v += __shfl_xor(v, 4); v += __shfl_xor(v, 8); v += __shfl_xor(v, 16); v += __shfl_xor(v, 32);
        sa[j] = v;
        float u = sb[j];
        u += __shfl_xor(u, 4); u += __shfl_xor(u, 8); u += __shfl_xor(u, 16); u += __shfl_xor(u, 32);
        sb[j] = u;
    }
    if (slot == 0) {
        float deg = (float)(end - beg);
        float inv = deg > 0.f ? 1.f / deg : 0.f;
        f4 r0 = *(const f4*)&t2r[(size_t)wid * 32 + d8];
        f4 r1 = *(const f4*)&t2r[(size_t)wid * 32 + d8 + 4];
        *(f4*)&out[(size_t)wid * 32 + d8]     = sa * inv + r0;
        *(f4*)&out[(size_t)wid * 32 + d8 + 4] = sb * inv + r1;
    }
}

extern "C" void kernel_launch(void* const* d_in, const int* in_sizes, int n_in,
                              void* d_out, int out_size, void* d_ws, size_t ws_size,
                              hipStream_t stream) {
    const float* x   = (const float*)d_in[0];
    const int*   ei  = (const int*)d_in[1];
    const float* W1l = (const float*)d_in[2];
    const float* b1  = (const float*)d_in[3];
    const float* W1r = (const float*)d_in[4];
    const float* W2l = (const float*)d_in[5];
    const float* b2  = (const float*)d_in[6];
    const float* W2r = (const float*)d_in[7];
    float* out = (float*)d_out;

    int N = in_sizes[0] / 64;
    int E = in_sizes[1] / 2;
    const int* src = ei;
    const int* dst = ei + E;
    int NB = (N + BSZ - 1) >> BSHIFT;   // 196

    char* ws = (char*)d_ws;
    size_t off = 0;
    auto alloc = [&](size_t bytes) { void* p = ws + off; off += (bytes + 255) & ~(size_t)255; return p; };
    int* bucket_cnt  = (int*)alloc((size_t)(NB + 1) * 4);   // +1: done counter
    int* bucket_base = (int*)alloc((size_t)(NB + 1) * 4);
    int* bucket_cur  = (int*)alloc((size_t)NB * 4);
    int* row_off     = (int*)alloc((size_t)(N + 1) * 4);
    int* col_src     = (int*)alloc((size_t)E * 4);
    unsigned int* bdata = (unsigned int*)alloc((size_t)E * 4);        // dead after CSR; reused as t2l
    unsigned char* t1l8 = (unsigned char*)alloc((size_t)N * 64 * 2);  // fp8 uses half; full reused as t2r
    float* t1r          = (float*)alloc((size_t)N * 64 * 4);          // h in-place

    unsigned short* t2l = (unsigned short*)bdata;  // N*32*2 <= E*4
    float* t2r          = (float*)t1l8;            // N*32*4 == N*64*2
    float* h = t1r;
    int* done = bucket_cnt + NB;

    hipMemsetAsync(bucket_cnt, 0, (size_t)(NB + 1) * 4, stream);
    const int NBH = 1024;
    int chunk = (E + NBH - 1) / NBH;
    int gb = (N + 63) / 64;

    // fused: gemm1 (blocks [0,gb)) + bhist (blocks [gb,gb+NBH)) + last-block bscan
    k_g1h<<<gb + NBH, 256, 0, stream>>>(x, W1l, W1r, N, gb, t1l8, t1r,
                                        dst, E, chunk, NBH, NB,
                                        bucket_cnt, done, bucket_base, bucket_cur, row_off);
    k_bscatter<<<NBH, 256, 0, stream>>>(src, dst, E, chunk, NB, bucket_cur, bdata);
    k_bucket_csr<<<NB, 256, 0, stream>>>(bdata, bucket_base, N, row_off, col_src);

    k_agg1<<<((size_t)N * 64 + 255) / 256, 256, 0, stream>>>(t1l8, row_off, col_src, b1, N, h);
    k_gemm2<<<gb, 256, 0, stream>>>(h, W2l, W2r, b2, N, t2l, t2r);
    k_agg2<<<((size_t)N * 64 + 255) / 256, 256, 0, stream>>>(t2l, t2r, row_off, col_src, N, out);
}

// Round 8
// 223.629 us; speedup vs baseline: 1.3804x; 1.3804x over previous
//
#include <hip/hip_runtime.h>

// GraphSAGE 2-layer, fp32 in/out. N=100000, E=1.6M, D: 64 -> 64 -> 32.
// Transform-first on BOTH layers. Gathered tensors compressed to 64 B rows:
//   t1l: fp8 e4m3 (64 dims), t2l: bf16 (32 dims).
// R7 lesson: heterogeneous block-split fusion regressed badly (serial
// 196-atomic scan tail + 50KB LDS forced on histogram blocks). Reverted.
// New this round: bucket_csr sorts each row's col_src by src-QUARTER
// (key = node*4 + quarter) so concurrent waves sweep the gather tables in
// ~1.6 MB phases -> stays under the 4 MiB per-XCD L2, removing the ~20 MB
// thrash component seen at R5 (71 MB FETCH vs ~51 MB compulsory).

typedef __attribute__((ext_vector_type(4))) float f4;
typedef __attribute__((ext_vector_type(2))) float f2;
typedef __attribute__((ext_vector_type(8))) unsigned short us8;
typedef __attribute__((ext_vector_type(4))) unsigned short us4;

#define BSHIFT 9
#define BSZ (1 << BSHIFT)   // 512 nodes per bucket
#define NBMAX 256

static __device__ inline unsigned short f2bf(float f) {
    union { float f; unsigned u; } v; v.f = f;
    unsigned u = v.u;
    u = (u + 0x7FFFu + ((u >> 16) & 1u)) >> 16;   // RNE
    return (unsigned short)u;
}
static __device__ inline float bf2f(unsigned short h) {
    union { unsigned u; float f; } v; v.u = ((unsigned)h) << 16; return v.f;
}

// ---------------- CSR build (bucketed) ----------------
__global__ __launch_bounds__(256) void k_bhist(const int* __restrict__ dst, int E, int chunk,
                                               int NB, int* __restrict__ bucket_cnt) {
    __shared__ int hist[NBMAX];
    int t = threadIdx.x;
    hist[t] = 0;
    __syncthreads();
    int lo = blockIdx.x * chunk, hi = min(lo + chunk, E);
    for (int e = lo + t; e < hi; e += 256) atomicAdd(&hist[dst[e] >> BSHIFT], 1);
    __syncthreads();
    if (t < NB) { int c = hist[t]; if (c) atomicAdd(&bucket_cnt[t], c); }
}

// one block, parallel wave scan over NB (<=256) buckets
__global__ __launch_bounds__(256) void k_bscan(const int* __restrict__ bucket_cnt, int NB, int E, int N,
                                               int* __restrict__ bucket_base, int* __restrict__ bucket_cur,
                                               int* __restrict__ row_off) {
    __shared__ int wt[4];
    int t = threadIdx.x;
    int v = (t < NB) ? bucket_cnt[t] : 0;
    int lane = t & 63, w = t >> 6;
    int p = v;
    for (int off = 1; off < 64; off <<= 1) { int u = __shfl_up(p, off); if (lane >= off) p += u; }
    if (lane == 63) wt[w] = p;
    __syncthreads();
    int wb = 0;
    for (int i = 0; i < w; i++) wb += wt[i];
    int incl = wb + p;
    int excl = incl - v;
    if (t < NB) { bucket_base[t] = excl; bucket_cur[t] = excl; }
    if (t == NB - 1) bucket_base[NB] = incl;
    if (t == 0) row_off[N] = E;
}

__global__ __launch_bounds__(256) void k_bscatter(const int* __restrict__ src, const int* __restrict__ dst,
                                                  int E, int chunk, int NB,
                                                  int* __restrict__ bucket_cur,
                                                  unsigned int* __restrict__ bdata) {
    __shared__ int lcnt[NBMAX], lbase[NBMAX], lcur[NBMAX];
    int t = threadIdx.x;
    lcnt[t] = 0;
    __syncthreads();
    int lo = blockIdx.x * chunk, hi = min(lo + chunk, E);
    for (int e = lo + t; e < hi; e += 256) atomicAdd(&lcnt[dst[e] >> BSHIFT], 1);
    __syncthreads();
    if (t < NB) { int c = lcnt[t]; lcur[t] = 0; if (c) lbase[t] = atomicAdd(&bucket_cur[t], c); }
    __syncthreads();
    for (int e = lo + t; e < hi; e += 256) {
        int d = dst[e];
        int b = d >> BSHIFT;
        int pos = lbase[b] + atomicAdd(&lcur[b], 1);
        bdata[pos] = ((unsigned)(d & (BSZ - 1)) << 17) | (unsigned)src[e];  // src < 2^17
    }
}

// One block per bucket: per-(node,quarter) histogram + 2048-key scan ->
// row_off + col_src sorted by src-quarter within each row.
__global__ __launch_bounds__(256) void k_bucket_csr(const unsigned int* __restrict__ bdata,
                                                    const int* __restrict__ bucket_base,
                                                    int N, int q1, int q2, int q3,
                                                    int* __restrict__ row_off,
                                                    int* __restrict__ col_src) {
    __shared__ int cnt[BSZ * 4];
    __shared__ int wt[4];
    int t = threadIdx.x;
    int b = blockIdx.x;
    int ebase = bucket_base[b], eend = bucket_base[b + 1];
#pragma unroll
    for (int i = 0; i < 8; i++) cnt[t * 8 + i] = 0;
    __syncthreads();
    for (int i = ebase + t; i < eend; i += 256) {
        unsigned v = bdata[i];
        int s = (int)(v & 0x1FFFFu);
        int q = (s >= q1) + (s >= q2) + (s >= q3);
        atomicAdd(&cnt[(int)(v >> 17) * 4 + q], 1);
    }
    __syncthreads();
    int loc[8]; int tsum = 0;
#pragma unroll
    for (int i = 0; i < 8; i++) { loc[i] = tsum; tsum += cnt[t * 8 + i]; }
    int lane = t & 63, w = t >> 6;
    int p = tsum;
    for (int off = 1; off < 64; off <<= 1) { int u = __shfl_up(p, off); if (lane >= off) p += u; }
    if (lane == 63) wt[w] = p;
    __syncthreads();
    int wb = 0;
    for (int i = 0; i < w; i++) wb += wt[i];
    int texcl = wb + p - tsum;
#pragma unroll
    for (int i = 0; i < 8; i++) {
        int key = t * 8 + i;
        int excl = texcl + loc[i];
        cnt[key] = excl;
        if ((key & 3) == 0) {
            int node = (b << BSHIFT) + (key >> 2);
            if (node < N) row_off[node] = ebase + excl;
        }
    }
    __syncthreads();
    for (int i = ebase + t; i < eend; i += 256) {
        unsigned v = bdata[i];
        int s = (int)(v & 0x1FFFFu);
        int q = (s >= q1) + (s >= q2) + (s >= q3);
        int pos = atomicAdd(&cnt[(int)(v >> 17) * 4 + q], 1);
        col_src[ebase + pos] = s;
    }
}

// ---------------- GEMM 1: t1l(fp8) = x@Wl, t1r(f32) = x@Wr ----------------
__global__ __launch_bounds__(256) void k_gemm1(const float* __restrict__ x,
                                               const float* __restrict__ Wl,
                                               const float* __restrict__ Wr, int N,
                                               unsigned char* __restrict__ t1l8,
                                               float* __restrict__ t1r) {
    __shared__ float sA[64 * 68];
    __shared__ float sWl[64 * 64];
    __shared__ float sWr[64 * 64];
    int t = threadIdx.x;
    int r0 = blockIdx.x * 64;
    for (int i = t; i < 1024; i += 256) {
        *(f4*)&sWl[i * 4] = *(const f4*)&Wl[i * 4];
        *(f4*)&sWr[i * 4] = *(const f4*)&Wr[i * 4];
    }
    {
        int row = t >> 4;
        int d0 = (t & 15) * 4;
#pragma unroll
        for (int kk = 0; kk < 4; kk++) {
            int r = row + kk * 16;
            f4 v = {0.f, 0.f, 0.f, 0.f};
            if (r0 + r < N) v = *(const f4*)&x[(size_t)(r0 + r) * 64 + d0];
            sA[(d0 + 0) * 68 + r] = v[0];
            sA[(d0 + 1) * 68 + r] = v[1];
            sA[(d0 + 2) * 68 + r] = v[2];
            sA[(d0 + 3) * 68 + r] = v[3];
        }
    }
    __syncthreads();
    int ty = t >> 4;
    int tx = t & 15;
    f4 accl[4] = {{0.f,0.f,0.f,0.f},{0.f,0.f,0.f,0.f},{0.f,0.f,0.f,0.f},{0.f,0.f,0.f,0.f}};
    f4 accr[4] = {{0.f,0.f,0.f,0.f},{0.f,0.f,0.f,0.f},{0.f,0.f,0.f,0.f},{0.f,0.f,0.f,0.f}};
#pragma unroll 4
    for (int d = 0; d < 64; d++) {
        f4 a  = *(const f4*)&sA[d * 68 + ty * 4];
        f4 wl = *(const f4*)&sWl[d * 64 + tx * 4];
        f4 wr = *(const f4*)&sWr[d * 64 + tx * 4];
#pragma unroll
        for (int r = 0; r < 4; r++) {
            accl[r] += a[r] * wl;
            accr[r] += a[r] * wr;
        }
    }
#pragma unroll
    for (int r = 0; r < 4; r++) {
        int rr = r0 + ty * 4 + r;
        if (rr < N) {
            unsigned w8 = __builtin_amdgcn_cvt_pk_fp8_f32(accl[r][0], accl[r][1], 0u, false);
            w8 = __builtin_amdgcn_cvt_pk_fp8_f32(accl[r][2], accl[r][3], w8, true);
            *(unsigned*)&t1l8[(size_t)rr * 64 + tx * 4] = w8;
            *(f4*)&t1r[(size_t)rr * 64 + tx * 4] = accr[r];
        }
    }
}

// ---------------- GEMM 2: t2l(bf16) = h@W2l, t2r(f32) = h@W2r + b2 ----------------
__global__ __launch_bounds__(256) void k_gemm2(const float* __restrict__ h,
                                               const float* __restrict__ Wl,
                                               const float* __restrict__ Wr,
                                               const float* __restrict__ b2, int N,
                                               unsigned short* __restrict__ t2l,
                                               float* __restrict__ t2r) {
    __shared__ float sA[64 * 68];
    __shared__ float sWl[64 * 32];
    __shared__ float sWr[64 * 32];
    int t = threadIdx.x;
    int r0 = blockIdx.x * 64;
    for (int i = t; i < 512; i += 256) {
        *(f4*)&sWl[i * 4] = *(const f4*)&Wl[i * 4];
        *(f4*)&sWr[i * 4] = *(const f4*)&Wr[i * 4];
    }
    {
        int row = t >> 4;
        int d0 = (t & 15) * 4;
#pragma unroll
        for (int kk = 0; kk < 4; kk++) {
            int r = row + kk * 16;
            f4 v = {0.f, 0.f, 0.f, 0.f};
            if (r0 + r < N) v = *(const f4*)&h[(size_t)(r0 + r) * 64 + d0];
            sA[(d0 + 0) * 68 + r] = v[0];
            sA[(d0 + 1) * 68 + r] = v[1];
            sA[(d0 + 2) * 68 + r] = v[2];
            sA[(d0 + 3) * 68 + r] = v[3];
        }
    }
    __syncthreads();
    int ty = t >> 4;
    int tx = t & 15;
    int m  = tx >> 3;
    int c0 = (tx & 7) * 4;
    const float* sW = m ? sWr : sWl;
    f4 acc[4] = {{0.f,0.f,0.f,0.f},{0.f,0.f,0.f,0.f},{0.f,0.f,0.f,0.f},{0.f,0.f,0.f,0.f}};
#pragma unroll 4
    for (int d = 0; d < 64; d++) {
        f4 a = *(const f4*)&sA[d * 68 + ty * 4];
        f4 w = *(const f4*)&sW[d * 32 + c0];
#pragma unroll
        for (int r = 0; r < 4; r++) acc[r] += a[r] * w;
    }
    if (m) {
        f4 bias = *(const f4*)&b2[c0];
#pragma unroll
        for (int r = 0; r < 4; r++) {
            int rr = r0 + ty * 4 + r;
            if (rr < N) *(f4*)&t2r[(size_t)rr * 32 + c0] = acc[r] + bias;
        }
    } else {
#pragma unroll
        for (int r = 0; r < 4; r++) {
            int rr = r0 + ty * 4 + r;
            if (rr < N) {
                us4 lv;
#pragma unroll
                for (int j = 0; j < 4; j++) lv[j] = f2bf(acc[r][j]);
                *(us4*)&t2l[(size_t)rr * 32 + c0] = lv;
            }
        }
    }
}

// ---------------- Layer-1 gather: h = relu(mean(t1l[nbrs]) + t1r + b1) ----------------
// wave/node; lane = (slot 0..3, dimgroup 0..15); 4 independent chains (MLP).
__global__ void k_agg1(const unsigned char* __restrict__ t1l8, const int* __restrict__ row_off,
                       const int* __restrict__ col_src, const float* __restrict__ b1,
                       int N, float* __restrict__ h /* == t1r, in-place */) {
    int wid = (blockIdx.x * blockDim.x + threadIdx.x) >> 6;
    int lane = threadIdx.x & 63;
    if (wid >= N) return;
    int beg = row_off[wid], end = row_off[wid + 1];
    int slot = lane >> 4;     // 0..3
    int g4 = (lane & 15) * 4; // dims g4..g4+3
    f4 s0 = {0.f,0.f,0.f,0.f}, s1 = {0.f,0.f,0.f,0.f};
    f4 s2 = {0.f,0.f,0.f,0.f}, s3 = {0.f,0.f,0.f,0.f};
    int k = beg + slot;
    for (; k + 12 < end; k += 16) {
        unsigned ua = *(const unsigned*)&t1l8[(size_t)col_src[k] * 64 + g4];
        unsigned ub = *(const unsigned*)&t1l8[(size_t)col_src[k + 4] * 64 + g4];
        unsigned uc = *(const unsigned*)&t1l8[(size_t)col_src[k + 8] * 64 + g4];
        unsigned ud = *(const unsigned*)&t1l8[(size_t)col_src[k + 12] * 64 + g4];
        f2 a0 = __builtin_amdgcn_cvt_pk_f32_fp8(ua, false);
        f2 a1 = __builtin_amdgcn_cvt_pk_f32_fp8(ua, true);
        f2 b0 = __builtin_amdgcn_cvt_pk_f32_fp8(ub, false);
        f2 b1x = __builtin_amdgcn_cvt_pk_f32_fp8(ub, true);
        f2 c0 = __builtin_amdgcn_cvt_pk_f32_fp8(uc, false);
        f2 c1 = __builtin_amdgcn_cvt_pk_f32_fp8(uc, true);
        f2 d0 = __builtin_amdgcn_cvt_pk_f32_fp8(ud, false);
        f2 d1 = __builtin_amdgcn_cvt_pk_f32_fp8(ud, true);
        s0[0] += a0[0]; s0[1] += a0[1]; s0[2] += a1[0]; s0[3] += a1[1];
        s1[0] += b0[0]; s1[1] += b0[1]; s1[2] += b1x[0]; s1[3] += b1x[1];
        s2[0] += c0[0]; s2[1] += c0[1]; s2[2] += c1[0]; s2[3] += c1[1];
        s3[0] += d0[0]; s3[1] += d0[1]; s3[2] += d1[0]; s3[3] += d1[1];
    }
    for (; k < end; k += 4) {
        unsigned ua = *(const unsigned*)&t1l8[(size_t)col_src[k] * 64 + g4];
        f2 a0 = __builtin_amdgcn_cvt_pk_f32_fp8(ua, false);
        f2 a1 = __builtin_amdgcn_cvt_pk_f32_fp8(ua, true);
        s0[0] += a0[0]; s0[1] += a0[1]; s0[2] += a1[0]; s0[3] += a1[1];
    }
    f4 sa = (s0 + s1) + (s2 + s3);
#pragma unroll
    for (int j = 0; j < 4; j++) {
        float v = sa[j];
        v += __shfl_xor(v, 16);
        v += __shfl_xor(v, 32);
        sa[j] = v;
    }
    if (slot == 0) {
        float deg = (float)(end - beg);
        float inv = deg > 0.f ? 1.f / deg : 0.f;
        f4 rr = *(const f4*)&h[(size_t)wid * 64 + g4];
        f4 bb = *(const f4*)&b1[g4];
        f4 o;
#pragma unroll
        for (int j = 0; j < 4; j++) {
            float v = sa[j] * inv + rr[j] + bb[j];
            o[j] = v > 0.f ? v : 0.f;
        }
        *(f4*)&h[(size_t)wid * 64 + g4] = o;
    }
}

// ---------------- Layer-2 gather: out = mean(t2l[nbrs]) + t2r ----------------
__global__ void k_agg2(const unsigned short* __restrict__ t2l, const float* __restrict__ t2r,
                       const int* __restrict__ row_off, const int* __restrict__ col_src,
                       int N, float* __restrict__ out) {
    int wid = (blockIdx.x * blockDim.x + threadIdx.x) >> 6;
    int lane = threadIdx.x & 63;
    if (wid >= N) return;
    int beg = row_off[wid], end = row_off[wid + 1];
    int slot = lane >> 2;
    int d8 = (lane & 3) * 8;
    f4 sa = {0.f,0.f,0.f,0.f}, sb = {0.f,0.f,0.f,0.f};
    f4 ta = {0.f,0.f,0.f,0.f}, tb = {0.f,0.f,0.f,0.f};
    int k = beg + slot;
    for (; k + 16 < end; k += 32) {
        us8 va = *(const us8*)&t2l[(size_t)col_src[k] * 32 + d8];
        us8 vb = *(const us8*)&t2l[(size_t)col_src[k + 16] * 32 + d8];
#pragma unroll
        for (int j = 0; j < 4; j++) {
            sa[j] += bf2f(va[j]);     sb[j] += bf2f(va[j + 4]);
            ta[j] += bf2f(vb[j]);     tb[j] += bf2f(vb[j + 4]);
        }
    }
    if (k < end) {
        us8 va = *(const us8*)&t2l[(size_t)col_src[k] * 32 + d8];
#pragma unroll
        for (int j = 0; j < 4; j++) { sa[j] += bf2f(va[j]); sb[j] += bf2f(va[j + 4]); }
    }
    sa += ta; sb += tb;
#pragma unroll
    for (int j = 0; j < 4; j++) {
        float v = sa[j];
        v += __shfl_xor(v, 4); v += __shfl_xor(v, 8); v += __shfl_xor(v, 16); v += __shfl_xor(v, 32);
        sa[j] = v;
        float u = sb[j];
        u += __shfl_xor(u, 4); u += __shfl_xor(u, 8); u += __shfl_xor(u, 16); u += __shfl_xor(u, 32);
        sb[j] = u;
    }
    if (slot == 0) {
        float deg = (float)(end - beg);
        float inv = deg > 0.f ? 1.f / deg : 0.f;
        f4 r0 = *(const f4*)&t2r[(size_t)wid * 32 + d8];
        f4 r1 = *(const f4*)&t2r[(size_t)wid * 32 + d8 + 4];
        *(f4*)&out[(size_t)wid * 32 + d8]     = sa * inv + r0;
        *(f4*)&out[(size_t)wid * 32 + d8 + 4] = sb * inv + r1;
    }
}

extern "C" void kernel_launch(void* const* d_in, const int* in_sizes, int n_in,
                              void* d_out, int out_size, void* d_ws, size_t ws_size,
                              hipStream_t stream) {
    const float* x   = (const float*)d_in[0];
    const int*   ei  = (const int*)d_in[1];
    const float* W1l = (const float*)d_in[2];
    const float* b1  = (const float*)d_in[3];
    const float* W1r = (const float*)d_in[4];
    const float* W2l = (const float*)d_in[5];
    const float* b2  = (const float*)d_in[6];
    const float* W2r = (const float*)d_in[7];
    float* out = (float*)d_out;

    int N = in_sizes[0] / 64;
    int E = in_sizes[1] / 2;
    const int* src = ei;
    const int* dst = ei + E;
    int NB = (N + BSZ - 1) >> BSHIFT;   // 196
    int q1 = N / 4, q2 = N / 2, q3 = (3 * (long long)N) / 4;

    char* ws = (char*)d_ws;
    size_t off = 0;
    auto alloc = [&](size_t bytes) { void* p = ws + off; off += (bytes + 255) & ~(size_t)255; return p; };
    int* bucket_cnt  = (int*)alloc((size_t)NB * 4);
    int* bucket_base = (int*)alloc((size_t)(NB + 1) * 4);
    int* bucket_cur  = (int*)alloc((size_t)NB * 4);
    int* row_off     = (int*)alloc((size_t)(N + 1) * 4);
    int* col_src     = (int*)alloc((size_t)E * 4);
    unsigned int* bdata = (unsigned int*)alloc((size_t)E * 4);        // dead after CSR; reused as t2l
    unsigned char* t1l8 = (unsigned char*)alloc((size_t)N * 64 * 2);  // fp8 uses half; full reused as t2r
    float* t1r          = (float*)alloc((size_t)N * 64 * 4);          // h in-place

    unsigned short* t2l = (unsigned short*)bdata;  // N*32*2 <= E*4
    float* t2r          = (float*)t1l8;            // N*32*4 == N*64*2
    float* h = t1r;

    hipMemsetAsync(bucket_cnt, 0, (size_t)NB * 4, stream);
    const int NBLK = 1024;
    int chunk = (E + NBLK - 1) / NBLK;
    k_bhist<<<NBLK, 256, 0, stream>>>(dst, E, chunk, NB, bucket_cnt);
    k_bscan<<<1, 256, 0, stream>>>(bucket_cnt, NB, E, N, bucket_base, bucket_cur, row_off);
    k_bscatter<<<NBLK, 256, 0, stream>>>(src, dst, E, chunk, NB, bucket_cur, bdata);
    k_bucket_csr<<<NB, 256, 0, stream>>>(bdata, bucket_base, N, q1, q2, q3, row_off, col_src);

    int gb = (N + 63) / 64;
    k_gemm1<<<gb, 256, 0, stream>>>(x, W1l, W1r, N, t1l8, t1r);
    k_agg1<<<((size_t)N * 64 + 255) / 256, 256, 0, stream>>>(t1l8, row_off, col_src, b1, N, h);
    k_gemm2<<<gb, 256, 0, stream>>>(h, W2l, W2r, b2, N, t2l, t2r);
    k_agg2<<<((size_t)N * 64 + 255) / 256, 256, 0, stream>>>(t2l, t2r, row_off, col_src, N, out);
}

// Round 9
// 199.044 us; speedup vs baseline: 1.5509x; 1.1235x over previous
//
#include <hip/hip_runtime.h>

// GraphSAGE 2-layer, fp32 in/out. N=100000, E=1.6M, D: 64 -> 64 -> 32.
// Transform-first on BOTH layers. Gathered tensors compressed to 64 B rows:
//   t1l: fp8 e4m3 (64 dims), t2l: bf16 (32 dims).
// R8 lesson: mean deg = 16 => wave-per-node (16 nbrs/iter) rarely completes
// a full unrolled iter; ~half the edges ran through a 1-deep remainder.
// Now: 16-lane GROUP per node (4 nodes/wave), lane = u32 of the 64 B row,
// 4-deep neighbor chain per group -> 16 independent gathers in flight/wave,
// no cross-lane reduction. Quarter-sort removed (R8: no FETCH change).

typedef __attribute__((ext_vector_type(4))) float f4;
typedef __attribute__((ext_vector_type(2))) float f2;
typedef __attribute__((ext_vector_type(4))) unsigned short us4;

#define BSHIFT 9
#define BSZ (1 << BSHIFT)   // 512 nodes per bucket
#define NBMAX 256

static __device__ inline unsigned short f2bf(float f) {
    union { float f; unsigned u; } v; v.f = f;
    unsigned u = v.u;
    u = (u + 0x7FFFu + ((u >> 16) & 1u)) >> 16;   // RNE
    return (unsigned short)u;
}
static __device__ inline float bf2f(unsigned short h) {
    union { unsigned u; float f; } v; v.u = ((unsigned)h) << 16; return v.f;
}

// ---------------- CSR build (bucketed) ----------------
__global__ __launch_bounds__(256) void k_bhist(const int* __restrict__ dst, int E, int chunk,
                                               int NB, int* __restrict__ bucket_cnt) {
    __shared__ int hist[NBMAX];
    int t = threadIdx.x;
    hist[t] = 0;
    __syncthreads();
    int lo = blockIdx.x * chunk, hi = min(lo + chunk, E);
    for (int e = lo + t; e < hi; e += 256) atomicAdd(&hist[dst[e] >> BSHIFT], 1);
    __syncthreads();
    if (t < NB) { int c = hist[t]; if (c) atomicAdd(&bucket_cnt[t], c); }
}

// one block, parallel wave scan over NB (<=256) buckets
__global__ __launch_bounds__(256) void k_bscan(const int* __restrict__ bucket_cnt, int NB, int E, int N,
                                               int* __restrict__ bucket_base, int* __restrict__ bucket_cur,
                                               int* __restrict__ row_off) {
    __shared__ int wt[4];
    int t = threadIdx.x;
    int v = (t < NB) ? bucket_cnt[t] : 0;
    int lane = t & 63, w = t >> 6;
    int p = v;
    for (int off = 1; off < 64; off <<= 1) { int u = __shfl_up(p, off); if (lane >= off) p += u; }
    if (lane == 63) wt[w] = p;
    __syncthreads();
    int wb = 0;
    for (int i = 0; i < w; i++) wb += wt[i];
    int incl = wb + p;
    int excl = incl - v;
    if (t < NB) { bucket_base[t] = excl; bucket_cur[t] = excl; }
    if (t == NB - 1) bucket_base[NB] = incl;
    if (t == 0) row_off[N] = E;
}

__global__ __launch_bounds__(256) void k_bscatter(const int* __restrict__ src, const int* __restrict__ dst,
                                                  int E, int chunk, int NB,
                                                  int* __restrict__ bucket_cur,
                                                  unsigned int* __restrict__ bdata) {
    __shared__ int lcnt[NBMAX], lbase[NBMAX], lcur[NBMAX];
    int t = threadIdx.x;
    lcnt[t] = 0;
    __syncthreads();
    int lo = blockIdx.x * chunk, hi = min(lo + chunk, E);
    for (int e = lo + t; e < hi; e += 256) atomicAdd(&lcnt[dst[e] >> BSHIFT], 1);
    __syncthreads();
    if (t < NB) { int c = lcnt[t]; lcur[t] = 0; if (c) lbase[t] = atomicAdd(&bucket_cur[t], c); }
    __syncthreads();
    for (int e = lo + t; e < hi; e += 256) {
        int d = dst[e];
        int b = d >> BSHIFT;
        int pos = lbase[b] + atomicAdd(&lcur[b], 1);
        bdata[pos] = ((unsigned)(d & (BSZ - 1)) << 17) | (unsigned)src[e];  // src < 2^17
    }
}

// One block per bucket: fine histogram + scan in LDS -> row_off, col_src.
__global__ __launch_bounds__(256) void k_bucket_csr(const unsigned int* __restrict__ bdata,
                                                    const int* __restrict__ bucket_base,
                                                    int N, int* __restrict__ row_off,
                                                    int* __restrict__ col_src) {
    __shared__ int fh[BSZ];
    __shared__ int wtot[4];
    int t = threadIdx.x;
    int b = blockIdx.x;
    int ebase = bucket_base[b], eend = bucket_base[b + 1];
    fh[2 * t] = 0; fh[2 * t + 1] = 0;
    __syncthreads();
    for (int i = ebase + t; i < eend; i += 256) atomicAdd(&fh[bdata[i] >> 17], 1);
    __syncthreads();
    int a0 = fh[2 * t], a1 = fh[2 * t + 1];
    int psum = a0 + a1;
    int lane = t & 63, w = t >> 6;
    int v = psum;
    for (int off = 1; off < 64; off <<= 1) { int u = __shfl_up(v, off); if (lane >= off) v += u; }
    if (lane == 63) wtot[w] = v;
    __syncthreads();
    int wbase = 0;
    for (int i = 0; i < w; i++) wbase += wtot[i];
    int excl = wbase + v - psum;
    int e0 = excl, e1 = excl + a0;
    int n0 = (b << BSHIFT) + 2 * t, n1 = n0 + 1;
    if (n0 < N) row_off[n0] = ebase + e0;
    if (n1 < N) row_off[n1] = ebase + e1;
    fh[2 * t] = e0; fh[2 * t + 1] = e1;
    __syncthreads();
    for (int i = ebase + t; i < eend; i += 256) {
        unsigned vv = bdata[i];
        int dl = vv >> 17;
        int pos = atomicAdd(&fh[dl], 1);
        col_src[ebase + pos] = (int)(vv & 0x1FFFFu);
    }
}

// ---------------- GEMM 1: t1l(fp8) = x@Wl, t1r(f32) = x@Wr ----------------
__global__ __launch_bounds__(256) void k_gemm1(const float* __restrict__ x,
                                               const float* __restrict__ Wl,
                                               const float* __restrict__ Wr, int N,
                                               unsigned char* __restrict__ t1l8,
                                               float* __restrict__ t1r) {
    __shared__ float sA[64 * 68];
    __shared__ float sWl[64 * 64];
    __shared__ float sWr[64 * 64];
    int t = threadIdx.x;
    int r0 = blockIdx.x * 64;
    for (int i = t; i < 1024; i += 256) {
        *(f4*)&sWl[i * 4] = *(const f4*)&Wl[i * 4];
        *(f4*)&sWr[i * 4] = *(const f4*)&Wr[i * 4];
    }
    {
        int row = t >> 4;
        int d0 = (t & 15) * 4;
#pragma unroll
        for (int kk = 0; kk < 4; kk++) {
            int r = row + kk * 16;
            f4 v = {0.f, 0.f, 0.f, 0.f};
            if (r0 + r < N) v = *(const f4*)&x[(size_t)(r0 + r) * 64 + d0];
            sA[(d0 + 0) * 68 + r] = v[0];
            sA[(d0 + 1) * 68 + r] = v[1];
            sA[(d0 + 2) * 68 + r] = v[2];
            sA[(d0 + 3) * 68 + r] = v[3];
        }
    }
    __syncthreads();
    int ty = t >> 4;
    int tx = t & 15;
    f4 accl[4] = {{0.f,0.f,0.f,0.f},{0.f,0.f,0.f,0.f},{0.f,0.f,0.f,0.f},{0.f,0.f,0.f,0.f}};
    f4 accr[4] = {{0.f,0.f,0.f,0.f},{0.f,0.f,0.f,0.f},{0.f,0.f,0.f,0.f},{0.f,0.f,0.f,0.f}};
#pragma unroll 4
    for (int d = 0; d < 64; d++) {
        f4 a  = *(const f4*)&sA[d * 68 + ty * 4];
        f4 wl = *(const f4*)&sWl[d * 64 + tx * 4];
        f4 wr = *(const f4*)&sWr[d * 64 + tx * 4];
#pragma unroll
        for (int r = 0; r < 4; r++) {
            accl[r] += a[r] * wl;
            accr[r] += a[r] * wr;
        }
    }
#pragma unroll
    for (int r = 0; r < 4; r++) {
        int rr = r0 + ty * 4 + r;
        if (rr < N) {
            unsigned w8 = __builtin_amdgcn_cvt_pk_fp8_f32(accl[r][0], accl[r][1], 0u, false);
            w8 = __builtin_amdgcn_cvt_pk_fp8_f32(accl[r][2], accl[r][3], w8, true);
            *(unsigned*)&t1l8[(size_t)rr * 64 + tx * 4] = w8;
            *(f4*)&t1r[(size_t)rr * 64 + tx * 4] = accr[r];
        }
    }
}

// ---------------- GEMM 2: t2l(bf16) = h@W2l, t2r(f32) = h@W2r + b2 ----------------
__global__ __launch_bounds__(256) void k_gemm2(const float* __restrict__ h,
                                               const float* __restrict__ Wl,
                                               const float* __restrict__ Wr,
                                               const float* __restrict__ b2, int N,
                                               unsigned short* __restrict__ t2l,
                                               float* __restrict__ t2r) {
    __shared__ float sA[64 * 68];
    __shared__ float sWl[64 * 32];
    __shared__ float sWr[64 * 32];
    int t = threadIdx.x;
    int r0 = blockIdx.x * 64;
    for (int i = t; i < 512; i += 256) {
        *(f4*)&sWl[i * 4] = *(const f4*)&Wl[i * 4];
        *(f4*)&sWr[i * 4] = *(const f4*)&Wr[i * 4];
    }
    {
        int row = t >> 4;
        int d0 = (t & 15) * 4;
#pragma unroll
        for (int kk = 0; kk < 4; kk++) {
            int r = row + kk * 16;
            f4 v = {0.f, 0.f, 0.f, 0.f};
            if (r0 + r < N) v = *(const f4*)&h[(size_t)(r0 + r) * 64 + d0];
            sA[(d0 + 0) * 68 + r] = v[0];
            sA[(d0 + 1) * 68 + r] = v[1];
            sA[(d0 + 2) * 68 + r] = v[2];
            sA[(d0 + 3) * 68 + r] = v[3];
        }
    }
    __syncthreads();
    int ty = t >> 4;
    int tx = t & 15;
    int m  = tx >> 3;
    int c0 = (tx & 7) * 4;
    const float* sW = m ? sWr : sWl;
    f4 acc[4] = {{0.f,0.f,0.f,0.f},{0.f,0.f,0.f,0.f},{0.f,0.f,0.f,0.f},{0.f,0.f,0.f,0.f}};
#pragma unroll 4
    for (int d = 0; d < 64; d++) {
        f4 a = *(const f4*)&sA[d * 68 + ty * 4];
        f4 w = *(const f4*)&sW[d * 32 + c0];
#pragma unroll
        for (int r = 0; r < 4; r++) acc[r] += a[r] * w;
    }
    if (m) {
        f4 bias = *(const f4*)&b2[c0];
#pragma unroll
        for (int r = 0; r < 4; r++) {
            int rr = r0 + ty * 4 + r;
            if (rr < N) *(f4*)&t2r[(size_t)rr * 32 + c0] = acc[r] + bias;
        }
    } else {
#pragma unroll
        for (int r = 0; r < 4; r++) {
            int rr = r0 + ty * 4 + r;
            if (rr < N) {
                us4 lv;
#pragma unroll
                for (int j = 0; j < 4; j++) lv[j] = f2bf(acc[r][j]);
                *(us4*)&t2l[(size_t)rr * 32 + c0] = lv;
            }
        }
    }
}

// ---------------- Layer-1 gather: h = relu(mean(t1l[nbrs]) + t1r + b1) ----------------
// 16-lane group per node (4 nodes/wave). Lane gl holds dims 4gl..4gl+3 (u32 of
// the 64 B fp8 row). 4-deep neighbor chain -> 16 gathers in flight per wave.
__global__ __launch_bounds__(256) void k_agg1(const unsigned char* __restrict__ t1l8,
                                              const int* __restrict__ row_off,
                                              const int* __restrict__ col_src,
                                              const float* __restrict__ b1,
                                              int N, float* __restrict__ h) {
    int gid = (blockIdx.x * blockDim.x + threadIdx.x) >> 4;
    int gl  = threadIdx.x & 15;
    if (gid >= N) return;
    int beg = row_off[gid], end = row_off[gid + 1];
    f4 a0 = {0.f,0.f,0.f,0.f}, a1 = {0.f,0.f,0.f,0.f};
    f4 a2 = {0.f,0.f,0.f,0.f}, a3 = {0.f,0.f,0.f,0.f};
    int k = beg;
    for (; k + 3 < end; k += 4) {
        int i0 = col_src[k], i1 = col_src[k + 1], i2 = col_src[k + 2], i3 = col_src[k + 3];
        unsigned u0 = *(const unsigned*)&t1l8[(size_t)i0 * 64 + gl * 4];
        unsigned u1 = *(const unsigned*)&t1l8[(size_t)i1 * 64 + gl * 4];
        unsigned u2 = *(const unsigned*)&t1l8[(size_t)i2 * 64 + gl * 4];
        unsigned u3 = *(const unsigned*)&t1l8[(size_t)i3 * 64 + gl * 4];
        f2 l0 = __builtin_amdgcn_cvt_pk_f32_fp8(u0, false), h0 = __builtin_amdgcn_cvt_pk_f32_fp8(u0, true);
        f2 l1 = __builtin_amdgcn_cvt_pk_f32_fp8(u1, false), h1 = __builtin_amdgcn_cvt_pk_f32_fp8(u1, true);
        f2 l2 = __builtin_amdgcn_cvt_pk_f32_fp8(u2, false), h2 = __builtin_amdgcn_cvt_pk_f32_fp8(u2, true);
        f2 l3 = __builtin_amdgcn_cvt_pk_f32_fp8(u3, false), h3 = __builtin_amdgcn_cvt_pk_f32_fp8(u3, true);
        a0[0] += l0[0]; a0[1] += l0[1]; a0[2] += h0[0]; a0[3] += h0[1];
        a1[0] += l1[0]; a1[1] += l1[1]; a1[2] += h1[0]; a1[3] += h1[1];
        a2[0] += l2[0]; a2[1] += l2[1]; a2[2] += h2[0]; a2[3] += h2[1];
        a3[0] += l3[0]; a3[1] += l3[1]; a3[2] += h3[0]; a3[3] += h3[1];
    }
    for (; k < end; k++) {
        unsigned u0 = *(const unsigned*)&t1l8[(size_t)col_src[k] * 64 + gl * 4];
        f2 l0 = __builtin_amdgcn_cvt_pk_f32_fp8(u0, false), h0 = __builtin_amdgcn_cvt_pk_f32_fp8(u0, true);
        a0[0] += l0[0]; a0[1] += l0[1]; a0[2] += h0[0]; a0[3] += h0[1];
    }
    f4 s = (a0 + a1) + (a2 + a3);
    float deg = (float)(end - beg);
    float inv = deg > 0.f ? 1.f / deg : 0.f;
    f4 rr = *(const f4*)&h[(size_t)gid * 64 + gl * 4];
    f4 bb = *(const f4*)&b1[gl * 4];
    f4 o;
#pragma unroll
    for (int j = 0; j < 4; j++) {
        float v = s[j] * inv + rr[j] + bb[j];
        o[j] = v > 0.f ? v : 0.f;
    }
    *(f4*)&h[(size_t)gid * 64 + gl * 4] = o;
}

// ---------------- Layer-2 gather: out = mean(t2l[nbrs]) + t2r ----------------
// 16-lane group per node. Lane gl holds dims 2gl..2gl+1 (u32 of the 64 B bf16 row).
__global__ __launch_bounds__(256) void k_agg2(const unsigned short* __restrict__ t2l,
                                              const float* __restrict__ t2r,
                                              const int* __restrict__ row_off,
                                              const int* __restrict__ col_src,
                                              int N, float* __restrict__ out) {
    int gid = (blockIdx.x * blockDim.x + threadIdx.x) >> 4;
    int gl  = threadIdx.x & 15;
    if (gid >= N) return;
    int beg = row_off[gid], end = row_off[gid + 1];
    f2 a0 = {0.f,0.f}, a1 = {0.f,0.f}, a2 = {0.f,0.f}, a3 = {0.f,0.f};
    int k = beg;
    for (; k + 3 < end; k += 4) {
        int i0 = col_src[k], i1 = col_src[k + 1], i2 = col_src[k + 2], i3 = col_src[k + 3];
        unsigned u0 = *(const unsigned*)&t2l[(size_t)i0 * 32 + gl * 2];
        unsigned u1 = *(const unsigned*)&t2l[(size_t)i1 * 32 + gl * 2];
        unsigned u2 = *(const unsigned*)&t2l[(size_t)i2 * 32 + gl * 2];
        unsigned u3 = *(const unsigned*)&t2l[(size_t)i3 * 32 + gl * 2];
        a0[0] += bf2f((unsigned short)(u0 & 0xFFFFu)); a0[1] += bf2f((unsigned short)(u0 >> 16));
        a1[0] += bf2f((unsigned short)(u1 & 0xFFFFu)); a1[1] += bf2f((unsigned short)(u1 >> 16));
        a2[0] += bf2f((unsigned short)(u2 & 0xFFFFu)); a2[1] += bf2f((unsigned short)(u2 >> 16));
        a3[0] += bf2f((unsigned short)(u3 & 0xFFFFu)); a3[1] += bf2f((unsigned short)(u3 >> 16));
    }
    for (; k < end; k++) {
        unsigned u0 = *(const unsigned*)&t2l[(size_t)col_src[k] * 32 + gl * 2];
        a0[0] += bf2f((unsigned short)(u0 & 0xFFFFu)); a0[1] += bf2f((unsigned short)(u0 >> 16));
    }
    f2 s = (a0 + a1) + (a2 + a3);
    float deg = (float)(end - beg);
    float inv = deg > 0.f ? 1.f / deg : 0.f;
    f2 rr = *(const f2*)&t2r[(size_t)gid * 32 + gl * 2];
    f2 o = {s[0] * inv + rr[0], s[1] * inv + rr[1]};
    *(f2*)&out[(size_t)gid * 32 + gl * 2] = o;
}

extern "C" void kernel_launch(void* const* d_in, const int* in_sizes, int n_in,
                              void* d_out, int out_size, void* d_ws, size_t ws_size,
                              hipStream_t stream) {
    const float* x   = (const float*)d_in[0];
    const int*   ei  = (const int*)d_in[1];
    const float* W1l = (const float*)d_in[2];
    const float* b1  = (const float*)d_in[3];
    const float* W1r = (const float*)d_in[4];
    const float* W2l = (const float*)d_in[5];
    const float* b2  = (const float*)d_in[6];
    const float* W2r = (const float*)d_in[7];
    float* out = (float*)d_out;

    int N = in_sizes[0] / 64;
    int E = in_sizes[1] / 2;
    const int* src = ei;
    const int* dst = ei + E;
    int NB = (N + BSZ - 1) >> BSHIFT;   // 196

    char* ws = (char*)d_ws;
    size_t off = 0;
    auto alloc = [&](size_t bytes) { void* p = ws + off; off += (bytes + 255) & ~(size_t)255; return p; };
    int* bucket_cnt  = (int*)alloc((size_t)NB * 4);
    int* bucket_base = (int*)alloc((size_t)(NB + 1) * 4);
    int* bucket_cur  = (int*)alloc((size_t)NB * 4);
    int* row_off     = (int*)alloc((size_t)(N + 1) * 4);
    int* col_src     = (int*)alloc((size_t)E * 4);
    unsigned int* bdata = (unsigned int*)alloc((size_t)E * 4);        // dead after CSR; reused as t2l
    unsigned char* t1l8 = (unsigned char*)alloc((size_t)N * 64 * 2);  // fp8 uses half; full reused as t2r
    float* t1r          = (float*)alloc((size_t)N * 64 * 4);          // h in-place

    unsigned short* t2l = (unsigned short*)bdata;  // N*32*2 <= E*4
    float* t2r          = (float*)t1l8;            // N*32*4 == N*64*2
    float* h = t1r;

    hipMemsetAsync(bucket_cnt, 0, (size_t)NB * 4, stream);
    const int NBLK = 1024;
    int chunk = (E + NBLK - 1) / NBLK;
    k_bhist<<<NBLK, 256, 0, stream>>>(dst, E, chunk, NB, bucket_cnt);
    k_bscan<<<1, 256, 0, stream>>>(bucket_cnt, NB, E, N, bucket_base, bucket_cur, row_off);
    k_bscatter<<<NBLK, 256, 0, stream>>>(src, dst, E, chunk, NB, bucket_cur, bdata);
    k_bucket_csr<<<NB, 256, 0, stream>>>(bdata, bucket_base, N, row_off, col_src);

    int gb = (N + 63) / 64;
    k_gemm1<<<gb, 256, 0, stream>>>(x, W1l, W1r, N, t1l8, t1r);
    k_agg1<<<((size_t)N * 16 + 255) / 256, 256, 0, stream>>>(t1l8, row_off, col_src, b1, N, h);
    k_gemm2<<<gb, 256, 0, stream>>>(h, W2l, W2r, b2, N, t2l, t2r);
    k_agg2<<<((size_t)N * 16 + 255) / 256, 256, 0, stream>>>(t2l, t2r, row_off, col_src, N, out);
}

// Round 10
// 163.582 us; speedup vs baseline: 1.8871x; 1.2168x over previous
//
#include <hip/hip_runtime.h>

// GraphSAGE 2-layer, fp32 in/out. N=100000, E=1.6M, D: 64 -> 64 -> 32.
// Transform-first on BOTH layers. Gathered tensors compressed to 64 B rows:
//   t1l: fp8 e4m3 (64 dims), t2l: bf16 (32 dims).
// Aggs: 16-lane group per node, 4-deep independent gather chains (R9: -24 us).
// CSR build (R9 rework): bhist writes per-(block,bucket) counts to cntmat;
// cscan turns cntmat into exact per-block offsets (deterministic); bscatter
// is single-pass with NO reservation atomics and NO dst re-read (R9: bscatter
// was 40 us = 2x LDS-atomic passes + 200K global reservation atomics).

typedef __attribute__((ext_vector_type(4))) float f4;
typedef __attribute__((ext_vector_type(2))) float f2;
typedef __attribute__((ext_vector_type(4))) unsigned short us4;

#define BSHIFT 9
#define BSZ (1 << BSHIFT)   // 512 nodes per bucket
#define NBMAX 256
#define NBLK 512            // histogram/scatter blocks (cntmat rows)

static __device__ inline unsigned short f2bf(float f) {
    union { float f; unsigned u; } v; v.f = f;
    unsigned u = v.u;
    u = (u + 0x7FFFu + ((u >> 16) & 1u)) >> 16;   // RNE
    return (unsigned short)u;
}
static __device__ inline float bf2f(unsigned short h) {
    union { unsigned u; float f; } v; v.u = ((unsigned)h) << 16; return v.f;
}

// ---------------- CSR build ----------------
// Per-block bucket histogram -> cntmat[blk*NB + b]. No global atomics.
__global__ __launch_bounds__(256) void k_bhist(const int* __restrict__ dst, int E, int chunk,
                                               int NB, int* __restrict__ cntmat) {
    __shared__ int hist[NBMAX];
    int t = threadIdx.x;
    hist[t] = 0;
    __syncthreads();
    int lo = blockIdx.x * chunk, hi = min(lo + chunk, E);
    for (int e = lo + t; e < hi; e += 256) atomicAdd(&hist[dst[e] >> BSHIFT], 1);
    __syncthreads();
    if (t < NB) cntmat[blockIdx.x * NB + t] = hist[t];
}

// One block per bucket: exclusive scan over the NBLK block-counts, in place.
// cntmat[k][b] becomes "offset of block k's bucket-b edges within bucket b".
__global__ __launch_bounds__(256) void k_cscan(int* __restrict__ cntmat, int NB,
                                               int* __restrict__ btot) {
    __shared__ int wt[4];
    int b = blockIdx.x;
    int t = threadIdx.x;
    int v0 = cntmat[(2 * t) * NB + b];
    int v1 = cntmat[(2 * t + 1) * NB + b];
    int tsum = v0 + v1;
    int lane = t & 63, w = t >> 6;
    int p = tsum;
    for (int off = 1; off < 64; off <<= 1) { int u = __shfl_up(p, off); if (lane >= off) p += u; }
    if (lane == 63) wt[w] = p;
    __syncthreads();
    int wb = 0;
    for (int i = 0; i < w; i++) wb += wt[i];
    int excl = wb + p - tsum;
    cntmat[(2 * t) * NB + b] = excl;
    cntmat[(2 * t + 1) * NB + b] = excl + v0;
    if (t == 255) btot[b] = wb + p;
}

// one block: scan bucket totals -> bucket_base
__global__ __launch_bounds__(256) void k_bscan(const int* __restrict__ btot, int NB, int E, int N,
                                               int* __restrict__ bucket_base,
                                               int* __restrict__ row_off) {
    __shared__ int wt[4];
    int t = threadIdx.x;
    int v = (t < NB) ? btot[t] : 0;
    int lane = t & 63, w = t >> 6;
    int p = v;
    for (int off = 1; off < 64; off <<= 1) { int u = __shfl_up(p, off); if (lane >= off) p += u; }
    if (lane == 63) wt[w] = p;
    __syncthreads();
    int wb = 0;
    for (int i = 0; i < w; i++) wb += wt[i];
    int incl = wb + p;
    int excl = incl - v;
    if (t < NB) bucket_base[t] = excl;
    if (t == NB - 1) bucket_base[NB] = incl;
    if (t == 0) row_off[N] = E;
}

// Single-pass scatter: per-block bases come from cntmat (deterministic).
__global__ __launch_bounds__(256) void k_bscatter(const int* __restrict__ src, const int* __restrict__ dst,
                                                  int E, int chunk, int NB,
                                                  const int* __restrict__ bucket_base,
                                                  const int* __restrict__ cntmat,
                                                  unsigned int* __restrict__ bdata) {
    __shared__ int lbase[NBMAX], lcur[NBMAX];
    int t = threadIdx.x;
    if (t < NB) { lbase[t] = bucket_base[t] + cntmat[blockIdx.x * NB + t]; lcur[t] = 0; }
    __syncthreads();
    int lo = blockIdx.x * chunk, hi = min(lo + chunk, E);
    for (int e = lo + t; e < hi; e += 256) {
        int d = dst[e];
        int b = d >> BSHIFT;
        int pos = lbase[b] + atomicAdd(&lcur[b], 1);
        bdata[pos] = ((unsigned)(d & (BSZ - 1)) << 17) | (unsigned)src[e];  // src < 2^17
    }
}

// One block per bucket: fine histogram + scan in LDS -> row_off, col_src.
__global__ __launch_bounds__(256) void k_bucket_csr(const unsigned int* __restrict__ bdata,
                                                    const int* __restrict__ bucket_base,
                                                    int N, int* __restrict__ row_off,
                                                    int* __restrict__ col_src) {
    __shared__ int fh[BSZ];
    __shared__ int wtot[4];
    int t = threadIdx.x;
    int b = blockIdx.x;
    int ebase = bucket_base[b], eend = bucket_base[b + 1];
    fh[2 * t] = 0; fh[2 * t + 1] = 0;
    __syncthreads();
    for (int i = ebase + t; i < eend; i += 256) atomicAdd(&fh[bdata[i] >> 17], 1);
    __syncthreads();
    int a0 = fh[2 * t], a1 = fh[2 * t + 1];
    int psum = a0 + a1;
    int lane = t & 63, w = t >> 6;
    int v = psum;
    for (int off = 1; off < 64; off <<= 1) { int u = __shfl_up(v, off); if (lane >= off) v += u; }
    if (lane == 63) wtot[w] = v;
    __syncthreads();
    int wbase = 0;
    for (int i = 0; i < w; i++) wbase += wtot[i];
    int excl = wbase + v - psum;
    int e0 = excl, e1 = excl + a0;
    int n0 = (b << BSHIFT) + 2 * t, n1 = n0 + 1;
    if (n0 < N) row_off[n0] = ebase + e0;
    if (n1 < N) row_off[n1] = ebase + e1;
    fh[2 * t] = e0; fh[2 * t + 1] = e1;
    __syncthreads();
    for (int i = ebase + t; i < eend; i += 256) {
        unsigned vv = bdata[i];
        int dl = vv >> 17;
        int pos = atomicAdd(&fh[dl], 1);
        col_src[ebase + pos] = (int)(vv & 0x1FFFFu);
    }
}

// ---------------- GEMM 1: t1l(fp8) = x@Wl, t1r(f32) = x@Wr ----------------
__global__ __launch_bounds__(256) void k_gemm1(const float* __restrict__ x,
                                               const float* __restrict__ Wl,
                                               const float* __restrict__ Wr, int N,
                                               unsigned char* __restrict__ t1l8,
                                               float* __restrict__ t1r) {
    __shared__ float sA[64 * 68];
    __shared__ float sWl[64 * 64];
    __shared__ float sWr[64 * 64];
    int t = threadIdx.x;
    int r0 = blockIdx.x * 64;
    for (int i = t; i < 1024; i += 256) {
        *(f4*)&sWl[i * 4] = *(const f4*)&Wl[i * 4];
        *(f4*)&sWr[i * 4] = *(const f4*)&Wr[i * 4];
    }
    {
        int row = t >> 4;
        int d0 = (t & 15) * 4;
#pragma unroll
        for (int kk = 0; kk < 4; kk++) {
            int r = row + kk * 16;
            f4 v = {0.f, 0.f, 0.f, 0.f};
            if (r0 + r < N) v = *(const f4*)&x[(size_t)(r0 + r) * 64 + d0];
            sA[(d0 + 0) * 68 + r] = v[0];
            sA[(d0 + 1) * 68 + r] = v[1];
            sA[(d0 + 2) * 68 + r] = v[2];
            sA[(d0 + 3) * 68 + r] = v[3];
        }
    }
    __syncthreads();
    int ty = t >> 4;
    int tx = t & 15;
    f4 accl[4] = {{0.f,0.f,0.f,0.f},{0.f,0.f,0.f,0.f},{0.f,0.f,0.f,0.f},{0.f,0.f,0.f,0.f}};
    f4 accr[4] = {{0.f,0.f,0.f,0.f},{0.f,0.f,0.f,0.f},{0.f,0.f,0.f,0.f},{0.f,0.f,0.f,0.f}};
#pragma unroll 4
    for (int d = 0; d < 64; d++) {
        f4 a  = *(const f4*)&sA[d * 68 + ty * 4];
        f4 wl = *(const f4*)&sWl[d * 64 + tx * 4];
        f4 wr = *(const f4*)&sWr[d * 64 + tx * 4];
#pragma unroll
        for (int r = 0; r < 4; r++) {
            accl[r] += a[r] * wl;
            accr[r] += a[r] * wr;
        }
    }
#pragma unroll
    for (int r = 0; r < 4; r++) {
        int rr = r0 + ty * 4 + r;
        if (rr < N) {
            unsigned w8 = __builtin_amdgcn_cvt_pk_fp8_f32(accl[r][0], accl[r][1], 0u, false);
            w8 = __builtin_amdgcn_cvt_pk_fp8_f32(accl[r][2], accl[r][3], w8, true);
            *(unsigned*)&t1l8[(size_t)rr * 64 + tx * 4] = w8;
            *(f4*)&t1r[(size_t)rr * 64 + tx * 4] = accr[r];
        }
    }
}

// ---------------- GEMM 2: t2l(bf16) = h@W2l, t2r(f32) = h@W2r + b2 ----------------
__global__ __launch_bounds__(256) void k_gemm2(const float* __restrict__ h,
                                               const float* __restrict__ Wl,
                                               const float* __restrict__ Wr,
                                               const float* __restrict__ b2, int N,
                                               unsigned short* __restrict__ t2l,
                                               float* __restrict__ t2r) {
    __shared__ float sA[64 * 68];
    __shared__ float sWl[64 * 32];
    __shared__ float sWr[64 * 32];
    int t = threadIdx.x;
    int r0 = blockIdx.x * 64;
    for (int i = t; i < 512; i += 256) {
        *(f4*)&sWl[i * 4] = *(const f4*)&Wl[i * 4];
        *(f4*)&sWr[i * 4] = *(const f4*)&Wr[i * 4];
    }
    {
        int row = t >> 4;
        int d0 = (t & 15) * 4;
#pragma unroll
        for (int kk = 0; kk < 4; kk++) {
            int r = row + kk * 16;
            f4 v = {0.f, 0.f, 0.f, 0.f};
            if (r0 + r < N) v = *(const f4*)&h[(size_t)(r0 + r) * 64 + d0];
            sA[(d0 + 0) * 68 + r] = v[0];
            sA[(d0 + 1) * 68 + r] = v[1];
            sA[(d0 + 2) * 68 + r] = v[2];
            sA[(d0 + 3) * 68 + r] = v[3];
        }
    }
    __syncthreads();
    int ty = t >> 4;
    int tx = t & 15;
    int m  = tx >> 3;
    int c0 = (tx & 7) * 4;
    const float* sW = m ? sWr : sWl;
    f4 acc[4] = {{0.f,0.f,0.f,0.f},{0.f,0.f,0.f,0.f},{0.f,0.f,0.f,0.f},{0.f,0.f,0.f,0.f}};
#pragma unroll 4
    for (int d = 0; d < 64; d++) {
        f4 a = *(const f4*)&sA[d * 68 + ty * 4];
        f4 w = *(const f4*)&sW[d * 32 + c0];
#pragma unroll
        for (int r = 0; r < 4; r++) acc[r] += a[r] * w;
    }
    if (m) {
        f4 bias = *(const f4*)&b2[c0];
#pragma unroll
        for (int r = 0; r < 4; r++) {
            int rr = r0 + ty * 4 + r;
            if (rr < N) *(f4*)&t2r[(size_t)rr * 32 + c0] = acc[r] + bias;
        }
    } else {
#pragma unroll
        for (int r = 0; r < 4; r++) {
            int rr = r0 + ty * 4 + r;
            if (rr < N) {
                us4 lv;
#pragma unroll
                for (int j = 0; j < 4; j++) lv[j] = f2bf(acc[r][j]);
                *(us4*)&t2l[(size_t)rr * 32 + c0] = lv;
            }
        }
    }
}

// ---------------- Layer-1 gather: h = relu(mean(t1l[nbrs]) + t1r + b1) ----------------
// 16-lane group per node (4 nodes/wave). Lane gl holds dims 4gl..4gl+3 (u32 of
// the 64 B fp8 row). 4-deep neighbor chain -> 16 gathers in flight per wave.
__global__ __launch_bounds__(256) void k_agg1(const unsigned char* __restrict__ t1l8,
                                              const int* __restrict__ row_off,
                                              const int* __restrict__ col_src,
                                              const float* __restrict__ b1,
                                              int N, float* __restrict__ h) {
    int gid = (blockIdx.x * blockDim.x + threadIdx.x) >> 4;
    int gl  = threadIdx.x & 15;
    if (gid >= N) return;
    int beg = row_off[gid], end = row_off[gid + 1];
    f4 a0 = {0.f,0.f,0.f,0.f}, a1 = {0.f,0.f,0.f,0.f};
    f4 a2 = {0.f,0.f,0.f,0.f}, a3 = {0.f,0.f,0.f,0.f};
    int k = beg;
    for (; k + 3 < end; k += 4) {
        int i0 = col_src[k], i1 = col_src[k + 1], i2 = col_src[k + 2], i3 = col_src[k + 3];
        unsigned u0 = *(const unsigned*)&t1l8[(size_t)i0 * 64 + gl * 4];
        unsigned u1 = *(const unsigned*)&t1l8[(size_t)i1 * 64 + gl * 4];
        unsigned u2 = *(const unsigned*)&t1l8[(size_t)i2 * 64 + gl * 4];
        unsigned u3 = *(const unsigned*)&t1l8[(size_t)i3 * 64 + gl * 4];
        f2 l0 = __builtin_amdgcn_cvt_pk_f32_fp8(u0, false), h0 = __builtin_amdgcn_cvt_pk_f32_fp8(u0, true);
        f2 l1 = __builtin_amdgcn_cvt_pk_f32_fp8(u1, false), h1 = __builtin_amdgcn_cvt_pk_f32_fp8(u1, true);
        f2 l2 = __builtin_amdgcn_cvt_pk_f32_fp8(u2, false), h2 = __builtin_amdgcn_cvt_pk_f32_fp8(u2, true);
        f2 l3 = __builtin_amdgcn_cvt_pk_f32_fp8(u3, false), h3 = __builtin_amdgcn_cvt_pk_f32_fp8(u3, true);
        a0[0] += l0[0]; a0[1] += l0[1]; a0[2] += h0[0]; a0[3] += h0[1];
        a1[0] += l1[0]; a1[1] += l1[1]; a1[2] += h1[0]; a1[3] += h1[1];
        a2[0] += l2[0]; a2[1] += l2[1]; a2[2] += h2[0]; a2[3] += h2[1];
        a3[0] += l3[0]; a3[1] += l3[1]; a3[2] += h3[0]; a3[3] += h3[1];
    }
    for (; k < end; k++) {
        unsigned u0 = *(const unsigned*)&t1l8[(size_t)col_src[k] * 64 + gl * 4];
        f2 l0 = __builtin_amdgcn_cvt_pk_f32_fp8(u0, false), h0 = __builtin_amdgcn_cvt_pk_f32_fp8(u0, true);
        a0[0] += l0[0]; a0[1] += l0[1]; a0[2] += h0[0]; a0[3] += h0[1];
    }
    f4 s = (a0 + a1) + (a2 + a3);
    float deg = (float)(end - beg);
    float inv = deg > 0.f ? 1.f / deg : 0.f;
    f4 rr = *(const f4*)&h[(size_t)gid * 64 + gl * 4];
    f4 bb = *(const f4*)&b1[gl * 4];
    f4 o;
#pragma unroll
    for (int j = 0; j < 4; j++) {
        float v = s[j] * inv + rr[j] + bb[j];
        o[j] = v > 0.f ? v : 0.f;
    }
    *(f4*)&h[(size_t)gid * 64 + gl * 4] = o;
}

// ---------------- Layer-2 gather: out = mean(t2l[nbrs]) + t2r ----------------
// 16-lane group per node. Lane gl holds dims 2gl..2gl+1 (u32 of the 64 B bf16 row).
__global__ __launch_bounds__(256) void k_agg2(const unsigned short* __restrict__ t2l,
                                              const float* __restrict__ t2r,
                                              const int* __restrict__ row_off,
                                              const int* __restrict__ col_src,
                                              int N, float* __restrict__ out) {
    int gid = (blockIdx.x * blockDim.x + threadIdx.x) >> 4;
    int gl  = threadIdx.x & 15;
    if (gid >= N) return;
    int beg = row_off[gid], end = row_off[gid + 1];
    f2 a0 = {0.f,0.f}, a1 = {0.f,0.f}, a2 = {0.f,0.f}, a3 = {0.f,0.f};
    int k = beg;
    for (; k + 3 < end; k += 4) {
        int i0 = col_src[k], i1 = col_src[k + 1], i2 = col_src[k + 2], i3 = col_src[k + 3];
        unsigned u0 = *(const unsigned*)&t2l[(size_t)i0 * 32 + gl * 2];
        unsigned u1 = *(const unsigned*)&t2l[(size_t)i1 * 32 + gl * 2];
        unsigned u2 = *(const unsigned*)&t2l[(size_t)i2 * 32 + gl * 2];
        unsigned u3 = *(const unsigned*)&t2l[(size_t)i3 * 32 + gl * 2];
        a0[0] += bf2f((unsigned short)(u0 & 0xFFFFu)); a0[1] += bf2f((unsigned short)(u0 >> 16));
        a1[0] += bf2f((unsigned short)(u1 & 0xFFFFu)); a1[1] += bf2f((unsigned short)(u1 >> 16));
        a2[0] += bf2f((unsigned short)(u2 & 0xFFFFu)); a2[1] += bf2f((unsigned short)(u2 >> 16));
        a3[0] += bf2f((unsigned short)(u3 & 0xFFFFu)); a3[1] += bf2f((unsigned short)(u3 >> 16));
    }
    for (; k < end; k++) {
        unsigned u0 = *(const unsigned*)&t2l[(size_t)col_src[k] * 32 + gl * 2];
        a0[0] += bf2f((unsigned short)(u0 & 0xFFFFu)); a0[1] += bf2f((unsigned short)(u0 >> 16));
    }
    f2 s = (a0 + a1) + (a2 + a3);
    float deg = (float)(end - beg);
    float inv = deg > 0.f ? 1.f / deg : 0.f;
    f2 rr = *(const f2*)&t2r[(size_t)gid * 32 + gl * 2];
    f2 o = {s[0] * inv + rr[0], s[1] * inv + rr[1]};
    *(f2*)&out[(size_t)gid * 32 + gl * 2] = o;
}

extern "C" void kernel_launch(void* const* d_in, const int* in_sizes, int n_in,
                              void* d_out, int out_size, void* d_ws, size_t ws_size,
                              hipStream_t stream) {
    const float* x   = (const float*)d_in[0];
    const int*   ei  = (const int*)d_in[1];
    const float* W1l = (const float*)d_in[2];
    const float* b1  = (const float*)d_in[3];
    const float* W1r = (const float*)d_in[4];
    const float* W2l = (const float*)d_in[5];
    const float* b2  = (const float*)d_in[6];
    const float* W2r = (const float*)d_in[7];
    float* out = (float*)d_out;

    int N = in_sizes[0] / 64;
    int E = in_sizes[1] / 2;
    const int* src = ei;
    const int* dst = ei + E;
    int NB = (N + BSZ - 1) >> BSHIFT;   // 196

    char* ws = (char*)d_ws;
    size_t off = 0;
    auto alloc = [&](size_t bytes) { void* p = ws + off; off += (bytes + 255) & ~(size_t)255; return p; };
    int* cntmat      = (int*)alloc((size_t)NBLK * NB * 4);   // per-(block,bucket) counts -> offsets
    int* btot        = (int*)alloc((size_t)NB * 4);
    int* bucket_base = (int*)alloc((size_t)(NB + 1) * 4);
    int* row_off     = (int*)alloc((size_t)(N + 1) * 4);
    int* col_src     = (int*)alloc((size_t)E * 4);
    unsigned int* bdata = (unsigned int*)alloc((size_t)E * 4);        // dead after CSR; reused as t2l
    unsigned char* t1l8 = (unsigned char*)alloc((size_t)N * 64 * 2);  // fp8 uses half; full reused as t2r
    float* t1r          = (float*)alloc((size_t)N * 64 * 4);          // h in-place

    unsigned short* t2l = (unsigned short*)bdata;  // N*32*2 <= E*4
    float* t2r          = (float*)t1l8;            // N*32*4 == N*64*2
    float* h = t1r;

    int chunk = (E + NBLK - 1) / NBLK;
    k_bhist<<<NBLK, 256, 0, stream>>>(dst, E, chunk, NB, cntmat);
    k_cscan<<<NB, 256, 0, stream>>>(cntmat, NB, btot);
    k_bscan<<<1, 256, 0, stream>>>(btot, NB, E, N, bucket_base, row_off);
    k_bscatter<<<NBLK, 256, 0, stream>>>(src, dst, E, chunk, NB, bucket_base, cntmat, bdata);
    k_bucket_csr<<<NB, 256, 0, stream>>>(bdata, bucket_base, N, row_off, col_src);

    int gb = (N + 63) / 64;
    k_gemm1<<<gb, 256, 0, stream>>>(x, W1l, W1r, N, t1l8, t1r);
    k_agg1<<<((size_t)N * 16 + 255) / 256, 256, 0, stream>>>(t1l8, row_off, col_src, b1, N, h);
    k_gemm2<<<gb, 256, 0, stream>>>(h, W2l, W2r, b2, N, t2l, t2r);
    k_agg2<<<((size_t)N * 16 + 255) / 256, 256, 0, stream>>>(t2l, t2r, row_off, col_src, N, out);
}

// Round 11
// 142.236 us; speedup vs baseline: 2.1703x; 1.1501x over previous
//
#include <hip/hip_runtime.h>

// GraphSAGE 2-layer, fp32 in/out. N=100000, E=1.6M, D: 64 -> 64 -> 32.
// Transform-first on BOTH layers. Gathered tensors compressed to 64 B rows:
//   t1l: fp8 e4m3 (64 dims), t2l: bf16 (32 dims). h: bf16 (12.8 MB).
// R10: both GEMMs moved to bf16 MFMA (16x16x32) -- fp32 vector GEMM was
// compute-bound at >=21 us (no fp32-input MFMA on CDNA4; no packed-fp32
// uplift). Weights staged transposed [n][k] bf16 in LDS, stride 72 ushorts
// (2-way bank aliasing = free). Fragment maps per learn_hip m89/m91.
// CSR build: bhist->cntmat, cscan (exact per-block offsets), single-pass
// scatter, bucket_csr. Aggs: 16-lane group/node, 4-deep gather chains.

typedef __attribute__((ext_vector_type(4))) float f4;
typedef __attribute__((ext_vector_type(2))) float f2;
typedef __attribute__((ext_vector_type(4))) unsigned short us4;
typedef __attribute__((ext_vector_type(8))) unsigned short us8;
typedef __attribute__((ext_vector_type(8))) short bfrag;   // 8 bf16 (4 VGPRs)

#define BSHIFT 9
#define BSZ (1 << BSHIFT)   // 512 nodes per bucket
#define NBMAX 256
#define NBLK 512            // histogram/scatter blocks (cntmat rows)
#define LSTR 72             // LDS row stride in ushorts (144 B)

static __device__ inline unsigned short f2bf(float f) {
    union { float f; unsigned u; } v; v.f = f;
    unsigned u = v.u;
    u = (u + 0x7FFFu + ((u >> 16) & 1u)) >> 16;   // RNE
    return (unsigned short)u;
}
static __device__ inline float bf2f(unsigned short h) {
    union { unsigned u; float f; } v; v.u = ((unsigned)h) << 16; return v.f;
}

// ---------------- CSR build ----------------
__global__ __launch_bounds__(256) void k_bhist(const int* __restrict__ dst, int E, int chunk,
                                               int NB, int* __restrict__ cntmat) {
    __shared__ int hist[NBMAX];
    int t = threadIdx.x;
    hist[t] = 0;
    __syncthreads();
    int lo = blockIdx.x * chunk, hi = min(lo + chunk, E);
    for (int e = lo + t; e < hi; e += 256) atomicAdd(&hist[dst[e] >> BSHIFT], 1);
    __syncthreads();
    if (t < NB) cntmat[blockIdx.x * NB + t] = hist[t];
}

__global__ __launch_bounds__(256) void k_cscan(int* __restrict__ cntmat, int NB,
                                               int* __restrict__ btot) {
    __shared__ int wt[4];
    int b = blockIdx.x;
    int t = threadIdx.x;
    int v0 = cntmat[(2 * t) * NB + b];
    int v1 = cntmat[(2 * t + 1) * NB + b];
    int tsum = v0 + v1;
    int lane = t & 63, w = t >> 6;
    int p = tsum;
    for (int off = 1; off < 64; off <<= 1) { int u = __shfl_up(p, off); if (lane >= off) p += u; }
    if (lane == 63) wt[w] = p;
    __syncthreads();
    int wb = 0;
    for (int i = 0; i < w; i++) wb += wt[i];
    int excl = wb + p - tsum;
    cntmat[(2 * t) * NB + b] = excl;
    cntmat[(2 * t + 1) * NB + b] = excl + v0;
    if (t == 255) btot[b] = wb + p;
}

__global__ __launch_bounds__(256) void k_bscan(const int* __restrict__ btot, int NB, int E, int N,
                                               int* __restrict__ bucket_base,
                                               int* __restrict__ row_off) {
    __shared__ int wt[4];
    int t = threadIdx.x;
    int v = (t < NB) ? btot[t] : 0;
    int lane = t & 63, w = t >> 6;
    int p = v;
    for (int off = 1; off < 64; off <<= 1) { int u = __shfl_up(p, off); if (lane >= off) p += u; }
    if (lane == 63) wt[w] = p;
    __syncthreads();
    int wb = 0;
    for (int i = 0; i < w; i++) wb += wt[i];
    int incl = wb + p;
    int excl = incl - v;
    if (t < NB) bucket_base[t] = excl;
    if (t == NB - 1) bucket_base[NB] = incl;
    if (t == 0) row_off[N] = E;
}

__global__ __launch_bounds__(256) void k_bscatter(const int* __restrict__ src, const int* __restrict__ dst,
                                                  int E, int chunk, int NB,
                                                  const int* __restrict__ bucket_base,
                                                  const int* __restrict__ cntmat,
                                                  unsigned int* __restrict__ bdata) {
    __shared__ int lbase[NBMAX], lcur[NBMAX];
    int t = threadIdx.x;
    if (t < NB) { lbase[t] = bucket_base[t] + cntmat[blockIdx.x * NB + t]; lcur[t] = 0; }
    __syncthreads();
    int lo = blockIdx.x * chunk, hi = min(lo + chunk, E);
    for (int e = lo + t; e < hi; e += 256) {
        int d = dst[e];
        int b = d >> BSHIFT;
        int pos = lbase[b] + atomicAdd(&lcur[b], 1);
        bdata[pos] = ((unsigned)(d & (BSZ - 1)) << 17) | (unsigned)src[e];  // src < 2^17
    }
}

__global__ __launch_bounds__(256) void k_bucket_csr(const unsigned int* __restrict__ bdata,
                                                    const int* __restrict__ bucket_base,
                                                    int N, int* __restrict__ row_off,
                                                    int* __restrict__ col_src) {
    __shared__ int fh[BSZ];
    __shared__ int wtot[4];
    int t = threadIdx.x;
    int b = blockIdx.x;
    int ebase = bucket_base[b], eend = bucket_base[b + 1];
    fh[2 * t] = 0; fh[2 * t + 1] = 0;
    __syncthreads();
    for (int i = ebase + t; i < eend; i += 256) atomicAdd(&fh[bdata[i] >> 17], 1);
    __syncthreads();
    int a0 = fh[2 * t], a1 = fh[2 * t + 1];
    int psum = a0 + a1;
    int lane = t & 63, w = t >> 6;
    int v = psum;
    for (int off = 1; off < 64; off <<= 1) { int u = __shfl_up(v, off); if (lane >= off) v += u; }
    if (lane == 63) wtot[w] = v;
    __syncthreads();
    int wbase = 0;
    for (int i = 0; i < w; i++) wbase += wtot[i];
    int excl = wbase + v - psum;
    int e0 = excl, e1 = excl + a0;
    int n0 = (b << BSHIFT) + 2 * t, n1 = n0 + 1;
    if (n0 < N) row_off[n0] = ebase + e0;
    if (n1 < N) row_off[n1] = ebase + e1;
    fh[2 * t] = e0; fh[2 * t + 1] = e1;
    __syncthreads();
    for (int i = ebase + t; i < eend; i += 256) {
        unsigned vv = bdata[i];
        int dl = vv >> 17;
        int pos = atomicAdd(&fh[dl], 1);
        col_src[ebase + pos] = (int)(vv & 0x1FFFFu);
    }
}

// ---------------- GEMM 1 (MFMA bf16): t1l(fp8) = x@Wl, t1r(f32) = x@Wr ----------------
// Block: 64 rows x 128 cols (Wl|Wr). 4 waves; wave = 16 rows x 128 cols
// = 8 output tiles x 2 K-halves of mfma_f32_16x16x32_bf16.
__global__ __launch_bounds__(256) void k_gemm1(const float* __restrict__ x,
                                               const float* __restrict__ Wl,
                                               const float* __restrict__ Wr, int N,
                                               unsigned char* __restrict__ t1l8,
                                               float* __restrict__ t1r) {
    __shared__ unsigned short sX[64 * LSTR];    // [row][k] bf16
    __shared__ unsigned short sW[128 * LSTR];   // [n][k] bf16 (transposed weights)
    int t = threadIdx.x;
    int r0 = blockIdx.x * 64;
    // stage weights transposed: 2*64*64 f32 = 2048 f4 reads
    for (int i = t; i < 2048; i += 256) {
        int which = i >> 10;            // 0 = Wl, 1 = Wr
        int rem = i & 1023;             // k*16 + c4
        int k = rem >> 4;
        int c4 = (rem & 15) * 4;
        f4 v = *(const f4*)&(which ? Wr : Wl)[k * 64 + c4];
        int nb = which * 64 + c4;
        sW[(nb + 0) * LSTR + k] = f2bf(v[0]);
        sW[(nb + 1) * LSTR + k] = f2bf(v[1]);
        sW[(nb + 2) * LSTR + k] = f2bf(v[2]);
        sW[(nb + 3) * LSTR + k] = f2bf(v[3]);
    }
    // stage x rows -> bf16
    {
        int row = t >> 2;               // 0..63
        int q = (t & 3) * 16;           // k quarter
        bool valid = (r0 + row) < N;
#pragma unroll
        for (int j = 0; j < 4; j++) {
            f4 v = {0.f, 0.f, 0.f, 0.f};
            if (valid) v = *(const f4*)&x[(size_t)(r0 + row) * 64 + q + j * 4];
            us4 bv;
            bv[0] = f2bf(v[0]); bv[1] = f2bf(v[1]); bv[2] = f2bf(v[2]); bv[3] = f2bf(v[3]);
            *(us4*)&sX[row * LSTR + q + j * 4] = bv;
        }
    }
    __syncthreads();
    int wv = t >> 6;          // wave 0..3 -> rows wv*16
    int l  = t & 63;
    int lm = l & 15;
    int lk = (l >> 4) * 8;
    f4 acc[8] = {{0.f,0.f,0.f,0.f},{0.f,0.f,0.f,0.f},{0.f,0.f,0.f,0.f},{0.f,0.f,0.f,0.f},
                 {0.f,0.f,0.f,0.f},{0.f,0.f,0.f,0.f},{0.f,0.f,0.f,0.f},{0.f,0.f,0.f,0.f}};
#pragma unroll
    for (int kh = 0; kh < 2; kh++) {
        bfrag a = *(const bfrag*)&sX[(wv * 16 + lm) * LSTR + kh * 32 + lk];
#pragma unroll
        for (int nt = 0; nt < 8; nt++) {
            bfrag b = *(const bfrag*)&sW[(nt * 16 + lm) * LSTR + kh * 32 + lk];
            acc[nt] = __builtin_amdgcn_mfma_f32_16x16x32_bf16(a, b, acc[nt], 0, 0, 0);
        }
    }
    int orow0 = r0 + wv * 16 + (l >> 4) * 4;
#pragma unroll
    for (int j = 0; j < 4; j++) {
        int rr = orow0 + j;
        if (rr < N) {
#pragma unroll
            for (int nt = 0; nt < 4; nt++) {     // n = nt*16+lm in 0..63 -> Wl -> fp8
                float v = acc[nt][j];
                unsigned w8 = __builtin_amdgcn_cvt_pk_fp8_f32(v, v, 0u, false);
                t1l8[(size_t)rr * 64 + nt * 16 + lm] = (unsigned char)(w8 & 0xFFu);
            }
#pragma unroll
            for (int nt = 0; nt < 4; nt++) {     // n-64 -> Wr col -> f32
                t1r[(size_t)rr * 64 + nt * 16 + lm] = acc[nt + 4][j];
            }
        }
    }
}

// ---------------- GEMM 2 (MFMA bf16): t2l(bf16) = h@W2l, t2r(f32) = h@W2r + b2 ----
// Block: 64 rows x 64 cols (W2l|W2r). 4 waves; wave = 16 rows x 64 cols.
__global__ __launch_bounds__(256) void k_gemm2(const unsigned short* __restrict__ hbf,
                                               const float* __restrict__ Wl,
                                               const float* __restrict__ Wr,
                                               const float* __restrict__ b2, int N,
                                               unsigned short* __restrict__ t2l,
                                               float* __restrict__ t2r) {
    __shared__ unsigned short sX[64 * LSTR];    // [row][k] bf16
    __shared__ unsigned short sW[64 * LSTR];    // [n][k] bf16, n: 0..31 Wl, 32..63 Wr
    int t = threadIdx.x;
    int r0 = blockIdx.x * 64;
    // stage weights transposed: 2*64*32 f32 = 1024 f4 reads
    for (int i = t; i < 1024; i += 256) {
        int which = i >> 9;             // 0 = Wl, 1 = Wr (512 f4 each)
        int rem = i & 511;              // k*8 + c4
        int k = rem >> 3;
        int c4 = (rem & 7) * 4;
        f4 v = *(const f4*)&(which ? Wr : Wl)[k * 32 + c4];
        int nb = which * 32 + c4;
        sW[(nb + 0) * LSTR + k] = f2bf(v[0]);
        sW[(nb + 1) * LSTR + k] = f2bf(v[1]);
        sW[(nb + 2) * LSTR + k] = f2bf(v[2]);
        sW[(nb + 3) * LSTR + k] = f2bf(v[3]);
    }
    // stage h rows (already bf16): 64 rows x 64 ushorts
    {
        int row = t >> 2;
        int q = (t & 3) * 16;
        us8 z = {0,0,0,0,0,0,0,0};
        us8 v0 = z, v1 = z;
        if (r0 + row < N) {
            v0 = *(const us8*)&hbf[(size_t)(r0 + row) * 64 + q];
            v1 = *(const us8*)&hbf[(size_t)(r0 + row) * 64 + q + 8];
        }
        *(us8*)&sX[row * LSTR + q] = v0;
        *(us8*)&sX[row * LSTR + q + 8] = v1;
    }
    __syncthreads();
    int wv = t >> 6;
    int l  = t & 63;
    int lm = l & 15;
    int lk = (l >> 4) * 8;
    f4 acc[4] = {{0.f,0.f,0.f,0.f},{0.f,0.f,0.f,0.f},{0.f,0.f,0.f,0.f},{0.f,0.f,0.f,0.f}};
#pragma unroll
    for (int kh = 0; kh < 2; kh++) {
        bfrag a = *(const bfrag*)&sX[(wv * 16 + lm) * LSTR + kh * 32 + lk];
#pragma unroll
        for (int nt = 0; nt < 4; nt++) {
            bfrag b = *(const bfrag*)&sW[(nt * 16 + lm) * LSTR + kh * 32 + lk];
            acc[nt] = __builtin_amdgcn_mfma_f32_16x16x32_bf16(a, b, acc[nt], 0, 0, 0);
        }
    }
    int orow0 = r0 + wv * 16 + (l >> 4) * 4;
#pragma unroll
    for (int j = 0; j < 4; j++) {
        int rr = orow0 + j;
        if (rr < N) {
#pragma unroll
            for (int nt = 0; nt < 2; nt++) {     // n = nt*16+lm in 0..31 -> t2l bf16
                t2l[(size_t)rr * 32 + nt * 16 + lm] = f2bf(acc[nt][j]);
            }
#pragma unroll
            for (int nt = 0; nt < 2; nt++) {     // c = n-32 -> t2r f32 + bias
                int c = nt * 16 + lm;
                t2r[(size_t)rr * 32 + c] = acc[nt + 2][j] + b2[c];
            }
        }
    }
}

// ---------------- Layer-1 gather: h(bf16) = relu(mean(t1l[nbrs]) + t1r + b1) ------
// 16-lane group per node (4 nodes/wave). Lane gl holds dims 4gl..4gl+3 (u32 of
// the 64 B fp8 row). 4-deep neighbor chain -> 16 gathers in flight per wave.
__global__ __launch_bounds__(256) void k_agg1(const unsigned char* __restrict__ t1l8,
                                              const int* __restrict__ row_off,
                                              const int* __restrict__ col_src,
                                              const float* __restrict__ b1,
                                              const float* __restrict__ t1r,
                                              int N, unsigned short* __restrict__ hbf) {
    int gid = (blockIdx.x * blockDim.x + threadIdx.x) >> 4;
    int gl  = threadIdx.x & 15;
    if (gid >= N) return;
    int beg = row_off[gid], end = row_off[gid + 1];
    f4 a0 = {0.f,0.f,0.f,0.f}, a1 = {0.f,0.f,0.f,0.f};
    f4 a2 = {0.f,0.f,0.f,0.f}, a3 = {0.f,0.f,0.f,0.f};
    int k = beg;
    for (; k + 3 < end; k += 4) {
        int i0 = col_src[k], i1 = col_src[k + 1], i2 = col_src[k + 2], i3 = col_src[k + 3];
        unsigned u0 = *(const unsigned*)&t1l8[(size_t)i0 * 64 + gl * 4];
        unsigned u1 = *(const unsigned*)&t1l8[(size_t)i1 * 64 + gl * 4];
        unsigned u2 = *(const unsigned*)&t1l8[(size_t)i2 * 64 + gl * 4];
        unsigned u3 = *(const unsigned*)&t1l8[(size_t)i3 * 64 + gl * 4];
        f2 l0 = __builtin_amdgcn_cvt_pk_f32_fp8(u0, false), h0 = __builtin_amdgcn_cvt_pk_f32_fp8(u0, true);
        f2 l1 = __builtin_amdgcn_cvt_pk_f32_fp8(u1, false), h1 = __builtin_amdgcn_cvt_pk_f32_fp8(u1, true);
        f2 l2 = __builtin_amdgcn_cvt_pk_f32_fp8(u2, false), h2 = __builtin_amdgcn_cvt_pk_f32_fp8(u2, true);
        f2 l3 = __builtin_amdgcn_cvt_pk_f32_fp8(u3, false), h3 = __builtin_amdgcn_cvt_pk_f32_fp8(u3, true);
        a0[0] += l0[0]; a0[1] += l0[1]; a0[2] += h0[0]; a0[3] += h0[1];
        a1[0] += l1[0]; a1[1] += l1[1]; a1[2] += h1[0]; a1[3] += h1[1];
        a2[0] += l2[0]; a2[1] += l2[1]; a2[2] += h2[0]; a2[3] += h2[1];
        a3[0] += l3[0]; a3[1] += l3[1]; a3[2] += h3[0]; a3[3] += h3[1];
    }
    for (; k < end; k++) {
        unsigned u0 = *(const unsigned*)&t1l8[(size_t)col_src[k] * 64 + gl * 4];
        f2 l0 = __builtin_amdgcn_cvt_pk_f32_fp8(u0, false), h0 = __builtin_amdgcn_cvt_pk_f32_fp8(u0, true);
        a0[0] += l0[0]; a0[1] += l0[1]; a0[2] += h0[0]; a0[3] += h0[1];
    }
    f4 s = (a0 + a1) + (a2 + a3);
    float deg = (float)(end - beg);
    float inv = deg > 0.f ? 1.f / deg : 0.f;
    f4 rr = *(const f4*)&t1r[(size_t)gid * 64 + gl * 4];
    f4 bb = *(const f4*)&b1[gl * 4];
    us4 ob;
#pragma unroll
    for (int j = 0; j < 4; j++) {
        float v = s[j] * inv + rr[j] + bb[j];
        ob[j] = f2bf(v > 0.f ? v : 0.f);
    }
    *(us4*)&hbf[(size_t)gid * 64 + gl * 4] = ob;
}

// ---------------- Layer-2 gather: out = mean(t2l[nbrs]) + t2r ----------------
// 16-lane group per node. Lane gl holds dims 2gl..2gl+1 (u32 of the 64 B bf16 row).
__global__ __launch_bounds__(256) void k_agg2(const unsigned short* __restrict__ t2l,
                                              const float* __restrict__ t2r,
                                              const int* __restrict__ row_off,
                                              const int* __restrict__ col_src,
                                              int N, float* __restrict__ out) {
    int gid = (blockIdx.x * blockDim.x + threadIdx.x) >> 4;
    int gl  = threadIdx.x & 15;
    if (gid >= N) return;
    int beg = row_off[gid], end = row_off[gid + 1];
    f2 a0 = {0.f,0.f}, a1 = {0.f,0.f}, a2 = {0.f,0.f}, a3 = {0.f,0.f};
    int k = beg;
    for (; k + 3 < end; k += 4) {
        int i0 = col_src[k], i1 = col_src[k + 1], i2 = col_src[k + 2], i3 = col_src[k + 3];
        unsigned u0 = *(const unsigned*)&t2l[(size_t)i0 * 32 + gl * 2];
        unsigned u1 = *(const unsigned*)&t2l[(size_t)i1 * 32 + gl * 2];
        unsigned u2 = *(const unsigned*)&t2l[(size_t)i2 * 32 + gl * 2];
        unsigned u3 = *(const unsigned*)&t2l[(size_t)i3 * 32 + gl * 2];
        a0[0] += bf2f((unsigned short)(u0 & 0xFFFFu)); a0[1] += bf2f((unsigned short)(u0 >> 16));
        a1[0] += bf2f((unsigned short)(u1 & 0xFFFFu)); a1[1] += bf2f((unsigned short)(u1 >> 16));
        a2[0] += bf2f((unsigned short)(u2 & 0xFFFFu)); a2[1] += bf2f((unsigned short)(u2 >> 16));
        a3[0] += bf2f((unsigned short)(u3 & 0xFFFFu)); a3[1] += bf2f((unsigned short)(u3 >> 16));
    }
    for (; k < end; k++) {
        unsigned u0 = *(const unsigned*)&t2l[(size_t)col_src[k] * 32 + gl * 2];
        a0[0] += bf2f((unsigned short)(u0 & 0xFFFFu)); a0[1] += bf2f((unsigned short)(u0 >> 16));
    }
    f2 s = (a0 + a1) + (a2 + a3);
    float deg = (float)(end - beg);
    float inv = deg > 0.f ? 1.f / deg : 0.f;
    f2 rr = *(const f2*)&t2r[(size_t)gid * 32 + gl * 2];
    f2 o = {s[0] * inv + rr[0], s[1] * inv + rr[1]};
    *(f2*)&out[(size_t)gid * 32 + gl * 2] = o;
}

extern "C" void kernel_launch(void* const* d_in, const int* in_sizes, int n_in,
                              void* d_out, int out_size, void* d_ws, size_t ws_size,
                              hipStream_t stream) {
    const float* x   = (const float*)d_in[0];
    const int*   ei  = (const int*)d_in[1];
    const float* W1l = (const float*)d_in[2];
    const float* b1  = (const float*)d_in[3];
    const float* W1r = (const float*)d_in[4];
    const float* W2l = (const float*)d_in[5];
    const float* b2  = (const float*)d_in[6];
    const float* W2r = (const float*)d_in[7];
    float* out = (float*)d_out;

    int N = in_sizes[0] / 64;
    int E = in_sizes[1] / 2;
    const int* src = ei;
    const int* dst = ei + E;
    int NB = (N + BSZ - 1) >> BSHIFT;   // 196

    char* ws = (char*)d_ws;
    size_t off = 0;
    auto alloc = [&](size_t bytes) { void* p = ws + off; off += (bytes + 255) & ~(size_t)255; return p; };
    int* cntmat      = (int*)alloc((size_t)NBLK * NB * 4);
    int* btot        = (int*)alloc((size_t)NB * 4);
    int* bucket_base = (int*)alloc((size_t)(NB + 1) * 4);
    int* row_off     = (int*)alloc((size_t)(N + 1) * 4);
    int* col_src     = (int*)alloc((size_t)E * 4);
    unsigned int* bdata = (unsigned int*)alloc((size_t)E * 4);        // dead after CSR; reused as t2l
    unsigned char* t1l8 = (unsigned char*)alloc((size_t)N * 64);      // fp8
    float* t1r          = (float*)alloc((size_t)N * 64 * 4);          // dead after agg1; reused as t2r
    unsigned short* hbf = (unsigned short*)alloc((size_t)N * 64 * 2); // h bf16

    unsigned short* t2l = (unsigned short*)bdata;  // N*32*2 == E*4
    float* t2r          = t1r;                     // N*32*4 <= N*64*4

    int chunk = (E + NBLK - 1) / NBLK;
    k_bhist<<<NBLK, 256, 0, stream>>>(dst, E, chunk, NB, cntmat);
    k_cscan<<<NB, 256, 0, stream>>>(cntmat, NB, btot);
    k_bscan<<<1, 256, 0, stream>>>(btot, NB, E, N, bucket_base, row_off);
    k_bscatter<<<NBLK, 256, 0, stream>>>(src, dst, E, chunk, NB, bucket_base, cntmat, bdata);
    k_bucket_csr<<<NB, 256, 0, stream>>>(bdata, bucket_base, N, row_off, col_src);

    int gb = (N + 63) / 64;
    k_gemm1<<<gb, 256, 0, stream>>>(x, W1l, W1r, N, t1l8, t1r);
    k_agg1<<<((size_t)N * 16 + 255) / 256, 256, 0, stream>>>(t1l8, row_off, col_src, b1, t1r, N, hbf);
    k_gemm2<<<gb, 256, 0, stream>>>(hbf, W2l, W2r, b2, N, t2l, t2r);
    k_agg2<<<((size_t)N * 16 + 255) / 256, 256, 0, stream>>>(t2l, t2r, row_off, col_src, N, out);
}